// Round 6
// baseline (1085.053 us; speedup 1.0000x reference)
//
#include <hip/hip_runtime.h>
#include <hip/hip_cooperative_groups.h>

namespace cg = cooperative_groups;

// Problem constants (fixed by the reference)
#define M 3
#define B 32
#define S 256
#define D 768
#define H 1024
#define MD (M * D)          // 2304
#define NP (M * (M - 1))    // 6 ordered (i,j) pairs
#define SCALE 0.03608439182435161f  // 1/sqrt(768)
#define LN_EPS 1e-5f

// Workspace layout (float offsets). Total 4312704 floats = ~17.3 MB.
#define OFF_WMU   0         // [M][D]
#define OFF_WLV   2304      // [M][D]
#define OFF_WPGQ  4608      // [M][D]
#define OFF_WPK   6912      // [NP][D]
#define OFF_CMU   11520     // [M]
#define OFF_CLV   11523     // [M]
#define OFF_CPGQ  11526     // [M]
#define OFF_CPK   11529     // [NP]
#define OFF_MU    11552     // [M][B][S]
#define OFF_LV    36128     // [M][B][S]
#define OFF_PKPRE 60704     // [NP][B][S]
#define OFF_PQPRE 109856    // [M][B]
#define OFF_Q     109952    // [M][B][D]
#define OFF_QBK   183680    // [NP][B]
#define OFF_QK    183872    // [NP][B][D]
#define OFF_FSUM  331328    // [NP][B][D]
#define OFF_AGG   478784    // [M][B][D]
#define OFF_E     552512    // [M][B][D]
#define OFF_G     626240    // [M][B][D]
#define OFF_FUSED 699968    // [B][MD]
#define OFF_KL    773696    // [1]
#define OFF_WKT   773760    // [M][D][D] Wk transposed (1769472 floats)
#define OFF_ARENA 2543232   // k-split partials / raw scores (max 1769472 floats)

__device__ __forceinline__ float wave_reduce(float v) {
    #pragma unroll
    for (int o = 32; o > 0; o >>= 1) v += __shfl_down(v, o, 64);
    return v;
}

__device__ __forceinline__ float sigmoidf(float x) {
    return 1.0f / (1.0f + __expf(-x));
}

__device__ __forceinline__ float dot4(float4 a, float4 b) {
    return a.x * b.x + a.y * b.y + a.z * b.z + a.w * b.w;
}

__device__ __forceinline__ void fma4(float4& a, float s, float4 w) {
    a.x += s * w.x; a.y += s * w.y; a.z += s * w.z; a.w += s * w.w;
}

struct MegaParams {
    const float *feats, *Wq, *bq, *Wk, *bk, *Wv, *bv;
    const float *pgq_w, *pgq_b, *pgk_w, *pgk_b;
    const float *mu_w, *mu_b, *lv_w, *lv_b, *dyn;
    const float *WE_w, *WE_b, *Wh_w, *Wh_b, *Wqc_w, *Wqc_b;
    const float *lnE_g, *lnE_b, *lnG_g, *lnG_b, *out_w, *out_b, *eps;
    float *ws, *out;
};

// ============ cooperative mega-kernel: all phases, grid.sync between ============
__global__ __launch_bounds__(256, 2) void k_mega(MegaParams p) {
    cg::grid_group grid = cg::this_grid();
    __shared__ __align__(16) char shraw[64 * 65 * 4];   // 16.6 KB, reused per phase
    float* ws = p.ws;
    const int tid = threadIdx.x;
    const int NB = gridDim.x;

    if (blockIdx.x == 0 && tid == 0) ws[OFF_KL] = 0.f;

    // ---- P0: prep (vec-dots 0..71, scalar consts 72..86, Wk transpose 87..518) ----
    for (int vb = blockIdx.x; vb < 519; vb += NB) {
        if (vb < 72) {
            int mat = vb / 12, rg = vb % 12;
            const float* Wm; const float *va, *vbv, *vc;
            float *oa, *ob, *oc; int nv;
            if (mat < 3) {
                int i = mat;
                Wm = p.Wq + i * D * D;
                va = p.mu_w + i * D; vbv = p.lv_w + i * D; vc = p.pgq_w + i * D;
                oa = ws + OFF_WMU + i * D; ob = ws + OFF_WLV + i * D; oc = ws + OFF_WPGQ + i * D;
                nv = 3;
            } else {
                int j = mat - 3;
                int i1 = (j == 0) ? 1 : 0, i2 = (j == 2) ? 1 : 2;
                int p1 = 2 * i1 + ((j < i1) ? j : j - 1);
                int p2 = 2 * i2 + ((j < i2) ? j : j - 1);
                Wm = p.Wk + j * D * D;
                va = p.pgk_w + i1 * D; vbv = p.pgk_w + i2 * D; vc = va;
                oa = ws + OFF_WPK + p1 * D; ob = ws + OFF_WPK + p2 * D; oc = oa;
                nv = 2;
            }
            int wave = tid >> 6, lane = tid & 63;
            const float4* va4 = (const float4*)va;
            const float4* vb4 = (const float4*)vbv;
            const float4* vc4 = (const float4*)vc;
            float4 A0 = va4[lane], A1 = va4[lane + 64], A2 = va4[lane + 128];
            float4 B0 = vb4[lane], B1 = vb4[lane + 64], B2 = vb4[lane + 128];
            float4 C0 = vc4[lane], C1 = vc4[lane + 64], C2 = vc4[lane + 128];
            int base = rg * 64 + wave * 16;
            for (int r = 0; r < 16; r += 2) {
                const float4* rowP = (const float4*)(Wm + (base + r) * D);
                const float4* rowQ = (const float4*)(Wm + (base + r + 1) * D);
                float4 x0 = rowP[lane], x1 = rowP[lane + 64], x2 = rowP[lane + 128];
                float4 y0 = rowQ[lane], y1 = rowQ[lane + 64], y2 = rowQ[lane + 128];
                float daP = dot4(x0, A0) + dot4(x1, A1) + dot4(x2, A2);
                float dbP = dot4(x0, B0) + dot4(x1, B1) + dot4(x2, B2);
                float dcP = dot4(x0, C0) + dot4(x1, C1) + dot4(x2, C2);
                float daQ = dot4(y0, A0) + dot4(y1, A1) + dot4(y2, A2);
                float dbQ = dot4(y0, B0) + dot4(y1, B1) + dot4(y2, B2);
                float dcQ = dot4(y0, C0) + dot4(y1, C1) + dot4(y2, C2);
                daP = wave_reduce(daP); dbP = wave_reduce(dbP);
                daQ = wave_reduce(daQ); dbQ = wave_reduce(dbQ);
                if (nv == 3) { dcP = wave_reduce(dcP); dcQ = wave_reduce(dcQ); }
                if (lane == 0) {
                    oa[base + r] = daP; ob[base + r] = dbP;
                    oa[base + r + 1] = daQ; ob[base + r + 1] = dbQ;
                    if (nv == 3) { oc[base + r] = dcP; oc[base + r + 1] = dcQ; }
                }
            }
        } else if (vb < 87) {
            int job = vb - 72;
            const float *a, *bvec; float bias; float* out;
            if (job < 3)      { int i = job;     a = p.bq + i * D; bvec = p.mu_w + i * D;  bias = p.mu_b[i];  out = ws + OFF_CMU + i; }
            else if (job < 6) { int i = job - 3; a = p.bq + i * D; bvec = p.lv_w + i * D;  bias = p.lv_b[i];  out = ws + OFF_CLV + i; }
            else if (job < 9) { int i = job - 6; a = p.bq + i * D; bvec = p.pgq_w + i * D; bias = p.pgq_b[i]; out = ws + OFF_CPGQ + i; }
            else {
                int pp = job - 9, i = pp / 2, c = pp % 2, j = c + (c >= i ? 1 : 0);
                a = p.bk + j * D; bvec = p.pgk_w + i * D; bias = p.pgk_b[i]; out = ws + OFF_CPK + pp;
            }
            float part = 0.f;
            if (tid < 192) part = dot4(((const float4*)a)[tid], ((const float4*)bvec)[tid]);
            part = wave_reduce(part);
            float* rsh = (float*)shraw;
            if ((tid & 63) == 0) rsh[tid >> 6] = part;
            __syncthreads();
            if (tid == 0) *out = rsh[0] + rsh[1] + rsh[2] + rsh[3] + bias;
        } else {
            int r = vb - 87;
            int j = r / 144; r = r % 144;
            int d0 = (r / 12) * 64, e0 = (r % 12) * 64;
            float* tile = (float*)shraw;   // [64][65]
            const float* src = p.Wk + j * D * D;
            for (int idx = tid; idx < 4096; idx += 256) {
                int rr = idx / 64, cc = idx % 64;
                tile[rr * 65 + cc] = src[(d0 + rr) * D + e0 + cc];
            }
            __syncthreads();
            float* dst = ws + OFF_WKT + j * D * D;
            for (int idx = tid; idx < 4096; idx += 256) {
                int rr = idx / 64, cc = idx % 64;
                dst[(e0 + rr) * D + d0 + cc] = tile[cc * 65 + rr];
            }
        }
        __syncthreads();
    }
    grid.sync();

    // ---- P1: Q partials (288 vb: i 3, bg 4 (8 b), kc 24 (32 k)) ----
    for (int vb = blockIdx.x; vb < 288; vb += NB) {
        int i = vb / 96, r = vb % 96, bg = r / 24, kc = r % 24;
        int kbase = kc * 32;
        float* xs = (float*)shraw;   // [32][8]
        {
            int d = tid / 8, bb = tid % 8;
            xs[d * 8 + bb] = p.feats[((size_t)(i * B + bg * 8 + bb) * S) * D + kbase + d];
        }
        __syncthreads();
        if (tid < 192) {
            int e4 = tid * 4;
            const float* Wm = p.Wq + i * D * D + kbase * D + e4;
            float4 acc[8];
            #pragma unroll
            for (int bb = 0; bb < 8; bb++) acc[bb] = make_float4(0.f, 0.f, 0.f, 0.f);
            for (int k = 0; k < 32; k++) {
                float4 w = *(const float4*)(Wm + k * D);
                float4 x0 = *(const float4*)&xs[k * 8];
                float4 x1 = *(const float4*)&xs[k * 8 + 4];
                fma4(acc[0], x0.x, w); fma4(acc[1], x0.y, w);
                fma4(acc[2], x0.z, w); fma4(acc[3], x0.w, w);
                fma4(acc[4], x1.x, w); fma4(acc[5], x1.y, w);
                fma4(acc[6], x1.z, w); fma4(acc[7], x1.w, w);
            }
            #pragma unroll
            for (int bb = 0; bb < 8; bb++)
                *(float4*)&ws[OFF_ARENA + kc * 73728 + (i * 32 + bg * 8 + bb) * 768 + e4] = acc[bb];
        }
        __syncthreads();
    }
    grid.sync();

    // ---- P2: reduce Q (24 kc) + bias; qbk for both pairs (96 vb: i,b) ----
    for (int vb = blockIdx.x; vb < 96; vb += NB) {
        int i = vb / B, b = vb % B;
        int fbase = (i * B + b) * D;
        float4* qsh = (float4*)shraw;
        float* redsh = (float*)(shraw + 192 * 16);
        if (tid < 192) {
            float4 a = *(const float4*)&p.bq[i * D + tid * 4];
            #pragma unroll
            for (int kc = 0; kc < 24; kc++) {
                float4 v = *(const float4*)&ws[OFF_ARENA + kc * 73728 + fbase + tid * 4];
                a.x += v.x; a.y += v.y; a.z += v.z; a.w += v.w;
            }
            *(float4*)&ws[OFF_Q + fbase + tid * 4] = a;
            qsh[tid] = a;
        }
        __syncthreads();
        int jA = (i == 0) ? 1 : 0, jB = (i == 2) ? 1 : 2;
        float pA_ = 0.f, pB_ = 0.f;
        if (tid < 192) {
            float4 q = qsh[tid];
            pA_ = dot4(q, *(const float4*)&p.bk[jA * D + tid * 4]);
            pB_ = dot4(q, *(const float4*)&p.bk[jB * D + tid * 4]);
        }
        pA_ = wave_reduce(pA_); pB_ = wave_reduce(pB_);
        int wave = tid >> 6, lane = tid & 63;
        if (lane == 0) { redsh[wave] = pA_; redsh[4 + wave] = pB_; }
        __syncthreads();
        if (tid == 0) {
            ws[OFF_QBK + (2 * i) * B + b]     = redsh[0] + redsh[1] + redsh[2] + redsh[3];
            ws[OFF_QBK + (2 * i + 1) * B + b] = redsh[4] + redsh[5] + redsh[6] + redsh[7];
        }
        __syncthreads();
    }
    grid.sync();

    // ---- P3: qk partials with WkT (288 vb: j 3, vg 8, kc 12 (64 k)) ----
    for (int vb = blockIdx.x; vb < 288; vb += NB) {
        int j = vb / 96, r = vb % 96, vg = r / 12, kc = r % 12;
        int kbase = kc * 64;
        int i1 = (j == 0) ? 1 : 0, i2 = (j == 2) ? 1 : 2;
        float* xs = (float*)shraw;   // [64][8]
        for (int idx = tid; idx < 512; idx += 256) {
            int d = idx / 8, v = idx % 8;
            int v64 = vg * 8 + v;
            int i_ = (v64 < 32) ? i1 : i2, b = v64 & 31;
            xs[d * 8 + v] = ws[OFF_Q + (i_ * 32 + b) * 768 + kbase + d];
        }
        __syncthreads();
        if (tid < 192) {
            int e4 = tid * 4;
            const float* Wm = ws + OFF_WKT + j * D * D + kbase * D + e4;
            float4 acc[8];
            #pragma unroll
            for (int bb = 0; bb < 8; bb++) acc[bb] = make_float4(0.f, 0.f, 0.f, 0.f);
            for (int k = 0; k < 64; k++) {
                float4 w = *(const float4*)(Wm + k * D);
                float4 x0 = *(const float4*)&xs[k * 8];
                float4 x1 = *(const float4*)&xs[k * 8 + 4];
                fma4(acc[0], x0.x, w); fma4(acc[1], x0.y, w);
                fma4(acc[2], x0.z, w); fma4(acc[3], x0.w, w);
                fma4(acc[4], x1.x, w); fma4(acc[5], x1.y, w);
                fma4(acc[6], x1.z, w); fma4(acc[7], x1.w, w);
            }
            #pragma unroll
            for (int v = 0; v < 8; v++)
                *(float4*)&ws[OFF_ARENA + kc * 147456 + (j * 64 + vg * 8 + v) * 768 + e4] = acc[v];
        }
        __syncthreads();
    }
    grid.sync();

    // ---- P4: reduce qk partials (144 vb x 256 thr) ----
    for (int vb = blockIdx.x; vb < 144; vb += NB) {
        int idx = vb * 256 + tid;
        int fidx = idx * 4;
        int pp = fidx / 24576, rem = fidx % 24576;
        int b = rem / 768, d = rem % 768;
        int i = pp / 2, c = pp % 2, j = c + (c >= i ? 1 : 0);
        int i1 = (j == 0) ? 1 : 0;
        int iidx = (i == i1) ? 0 : 1;
        int vg = iidx * 32 + b;
        float4 a = make_float4(0.f, 0.f, 0.f, 0.f);
        #pragma unroll
        for (int kc = 0; kc < 12; kc++) {
            float4 q = *(const float4*)&ws[OFF_ARENA + kc * 147456 + (j * 64 + vg) * 768 + d];
            a.x += q.x; a.y += q.y; a.z += q.z; a.w += q.w;
        }
        *(float4*)&ws[OFF_QK + fidx] = a;
    }
    grid.sync();

    // ---- P5: fused score + stats (384 vb: j, b, kc 4). One feats pass for both. ----
    for (int vb = blockIdx.x; vb < 384; vb += NB) {
        int j = vb / 128, r = vb % 128, b = r / 4, kc = r % 4;
        int i1 = (j == 0) ? 1 : 0, i2 = (j == 2) ? 1 : 2;
        int pA = 2 * i1 + ((j < i1) ? j : j - 1);
        int pB = 2 * i2 + ((j < i2) ? j : j - 1);
        int wave = tid >> 6, lane = tid & 63;
        const float4* qa4 = (const float4*)(ws + OFF_QK + (pA * B + b) * D);
        const float4* qb4 = (const float4*)(ws + OFF_QK + (pB * B + b) * D);
        float4 qA0 = qa4[lane], qA1 = qa4[lane + 64], qA2 = qa4[lane + 128];
        float4 qB0 = qb4[lane], qB1 = qb4[lane + 64], qB2 = qb4[lane + 128];
        const float4* wmu4 = (const float4*)(ws + OFF_WMU + j * D);
        const float4* wlv4 = (const float4*)(ws + OFF_WLV + j * D);
        const float4* wk04 = (const float4*)(ws + OFF_WPK + pA * D);
        const float4* wk14 = (const float4*)(ws + OFF_WPK + pB * D);
        float4 U0 = wmu4[lane], U1 = wmu4[lane + 64], U2 = wmu4[lane + 128];
        float4 L0 = wlv4[lane], L1 = wlv4[lane + 64], L2 = wlv4[lane + 128];
        float4 K00 = wk04[lane], K01 = wk04[lane + 64], K02 = wk04[lane + 128];
        float4 K10 = wk14[lane], K11 = wk14[lane + 64], K12 = wk14[lane + 128];
        const float* fb = p.feats + ((j * B + b) * S) * D;
        float* scA = ws + OFF_ARENA + ((j * B + b) * 2) * S;
        float* scB = scA + S;
        float cmu = ws[OFF_CMU + j], clv = ws[OFF_CLV + j];
        float cpk0 = ws[OFF_CPK + pA], cpk1 = ws[OFF_CPK + pB];
        if (kc == 0 && wave == 0) {
            const float4* wg4 = (const float4*)(ws + OFF_WPGQ + j * D);
            const float4* f0 = (const float4*)fb;
            float dd = dot4(f0[lane], wg4[lane]) + dot4(f0[lane + 64], wg4[lane + 64])
                     + dot4(f0[lane + 128], wg4[lane + 128]);
            dd = wave_reduce(dd);
            if (lane == 0) ws[OFF_PQPRE + j * B + b] = dd + ws[OFF_CPGQ + j];
        }
        int k0 = kc * 64 + wave * 16;
        float klsum = 0.f;
        for (int k = k0; k < k0 + 16; k += 2) {
            const float4* fA = (const float4*)(fb + k * D);
            const float4* fB = (const float4*)(fb + (k + 1) * D);
            float4 a0 = fA[lane], a1 = fA[lane + 64], a2 = fA[lane + 128];
            float4 b0 = fB[lane], b1 = fB[lane + 64], b2 = fB[lane + 128];
            float sa1 = dot4(a0, qA0) + dot4(a1, qA1) + dot4(a2, qA2);
            float sb1 = dot4(a0, qB0) + dot4(a1, qB1) + dot4(a2, qB2);
            float mu1 = dot4(a0, U0) + dot4(a1, U1) + dot4(a2, U2);
            float lv1 = dot4(a0, L0) + dot4(a1, L1) + dot4(a2, L2);
            float p01 = dot4(a0, K00) + dot4(a1, K01) + dot4(a2, K02);
            float p11 = dot4(a0, K10) + dot4(a1, K11) + dot4(a2, K12);
            float sa2 = dot4(b0, qA0) + dot4(b1, qA1) + dot4(b2, qA2);
            float sb2 = dot4(b0, qB0) + dot4(b1, qB1) + dot4(b2, qB2);
            float mu2 = dot4(b0, U0) + dot4(b1, U1) + dot4(b2, U2);
            float lv2 = dot4(b0, L0) + dot4(b1, L1) + dot4(b2, L2);
            float p02 = dot4(b0, K00) + dot4(b1, K01) + dot4(b2, K02);
            float p12 = dot4(b0, K10) + dot4(b1, K11) + dot4(b2, K12);
            sa1 = wave_reduce(sa1); sb1 = wave_reduce(sb1);
            mu1 = wave_reduce(mu1); lv1 = wave_reduce(lv1);
            p01 = wave_reduce(p01); p11 = wave_reduce(p11);
            sa2 = wave_reduce(sa2); sb2 = wave_reduce(sb2);
            mu2 = wave_reduce(mu2); lv2 = wave_reduce(lv2);
            p02 = wave_reduce(p02); p12 = wave_reduce(p12);
            if (lane == 0) {
                scA[k] = sa1; scB[k] = sb1; scA[k + 1] = sa2; scB[k + 1] = sb2;
                float m1 = mu1 + cmu, l1 = lv1 + clv;
                float m2 = mu2 + cmu, l2 = lv2 + clv;
                int row = (j * B + b) * S + k;
                ws[OFF_MU + row] = m1;      ws[OFF_MU + row + 1] = m2;
                ws[OFF_LV + row] = l1;      ws[OFF_LV + row + 1] = l2;
                ws[OFF_PKPRE + (pA * B + b) * S + k]     = p01 + cpk0;
                ws[OFF_PKPRE + (pA * B + b) * S + k + 1] = p02 + cpk0;
                ws[OFF_PKPRE + (pB * B + b) * S + k]     = p11 + cpk1;
                ws[OFF_PKPRE + (pB * B + b) * S + k + 1] = p12 + cpk1;
                klsum += 2.0f + l1 + l2 - m1 * m1 - m2 * m2 - __expf(l1) - __expf(l2);
            }
        }
        if (lane == 0) atomicAdd(ws + OFF_KL, -klsum);
    }
    grid.sync();

    // ---- P6: gates + softmax + weighted feats sum (288 vb: j, b, dc 3) ----
    for (int vb = blockIdx.x; vb < 288; vb += NB) {
        int j = vb / 96, r = vb % 96, b = r / 3, dc = r % 3;
        int i1 = (j == 0) ? 1 : 0, i2 = (j == 2) ? 1 : 2;
        int pA = 2 * i1 + ((j < i1) ? j : j - 1);
        int pB = 2 * i2 + ((j < i2) ? j : j - 1);
        float* sA = (float*)shraw;
        float* sB = sA + 256;
        float* redm = sB + 256;
        int t = tid;
        float dynv = p.dyn[0];
        const float* rawA = ws + OFF_ARENA + ((j * B + b) * 2) * S;
        const float* rawB = rawA + S;
        {
            float muk = ws[OFF_MU + (i1 * B + b) * S + t];
            float lvk = ws[OFF_LV + (i1 * B + b) * S + t];
            float ek  = p.eps[(pA * B + b) * S + t];
            float g   = sigmoidf(muk + dynv * __expf(0.5f * lvk) * ek);
            float pk  = sigmoidf(ws[OFF_PKPRE + (pA * B + b) * S + t]) * g;
            float mu0 = ws[OFF_MU + (i1 * B + b) * S];
            float lv0 = ws[OFF_LV + (i1 * B + b) * S];
            float e0  = p.eps[(pA * B + b) * S];
            float g0  = sigmoidf(mu0 + dynv * __expf(0.5f * lv0) * e0);
            float pq  = sigmoidf(ws[OFF_PQPRE + i1 * B + b]) * g0;
            float qbk = ws[OFF_QBK + pA * B + b];
            sA[t] = (rawA[t] + qbk) * SCALE * pq * pk;
            muk = ws[OFF_MU + (i2 * B + b) * S + t];
            lvk = ws[OFF_LV + (i2 * B + b) * S + t];
            ek  = p.eps[(pB * B + b) * S + t];
            g   = sigmoidf(muk + dynv * __expf(0.5f * lvk) * ek);
            pk  = sigmoidf(ws[OFF_PKPRE + (pB * B + b) * S + t]) * g;
            mu0 = ws[OFF_MU + (i2 * B + b) * S];
            lv0 = ws[OFF_LV + (i2 * B + b) * S];
            e0  = p.eps[(pB * B + b) * S];
            g0  = sigmoidf(mu0 + dynv * __expf(0.5f * lv0) * e0);
            pq  = sigmoidf(ws[OFF_PQPRE + i2 * B + b]) * g0;
            qbk = ws[OFF_QBK + pB * B + b];
            sB[t] = (rawB[t] + qbk) * SCALE * pq * pk;
        }
        __syncthreads();
        redm[t] = sA[t]; __syncthreads();
        for (int st = 128; st > 0; st >>= 1) { if (t < st) redm[t] = fmaxf(redm[t], redm[t + st]); __syncthreads(); }
        float mxA = redm[0]; __syncthreads();
        float wA = __expf(sA[t] - mxA);
        redm[t] = wA; __syncthreads();
        for (int st = 128; st > 0; st >>= 1) { if (t < st) redm[t] += redm[t + st]; __syncthreads(); }
        float sumA = redm[0]; __syncthreads();
        sA[t] = wA / sumA;
        __syncthreads();
        redm[t] = sB[t]; __syncthreads();
        for (int st = 128; st > 0; st >>= 1) { if (t < st) redm[t] = fmaxf(redm[t], redm[t + st]); __syncthreads(); }
        float mxB = redm[0]; __syncthreads();
        float wB = __expf(sB[t] - mxB);
        redm[t] = wB; __syncthreads();
        for (int st = 128; st > 0; st >>= 1) { if (t < st) redm[t] += redm[t + st]; __syncthreads(); }
        float sumB = redm[0]; __syncthreads();
        sB[t] = wB / sumB;
        __syncthreads();
        int dim = dc * 256 + t;
        const float* fcol = p.feats + ((j * B + b) * S) * D + dim;
        float accA = 0.f, accB = 0.f;
        #pragma unroll 8
        for (int k = 0; k < S; k++) {
            float fv = fcol[k * D];
            accA += sA[k] * fv;
            accB += sB[k] * fv;
        }
        ws[OFF_FSUM + (pA * B + b) * D + dim] = accA;
        ws[OFF_FSUM + (pB * B + b) * D + dim] = accB;
        __syncthreads();
    }
    grid.sync();

    // ---- P7: agg partials (288 vb: i 3, bg 4, kc 24 (32 k)) ----
    for (int vb = blockIdx.x; vb < 288; vb += NB) {
        int i = vb / 96, r = vb % 96, bg = r / 24, kc = r % 24;
        int kbase = kc * 32;
        int j0 = (i == 0) ? 1 : 0, j1 = (i == 2) ? 1 : 2;
        int p0 = 2 * i, p1 = 2 * i + 1;
        float* xs0 = (float*)shraw;            // [32][8]
        float* xs1 = xs0 + 256;
        {
            int d = tid / 8, bb = tid % 8;
            xs0[d * 8 + bb] = ws[OFF_FSUM + (p0 * B + bg * 8 + bb) * D + kbase + d];
            xs1[d * 8 + bb] = ws[OFF_FSUM + (p1 * B + bg * 8 + bb) * D + kbase + d];
        }
        __syncthreads();
        if (tid < 192) {
            int e4 = tid * 4;
            const float* W0 = p.Wv + j0 * D * D + kbase * D + e4;
            const float* W1 = p.Wv + j1 * D * D + kbase * D + e4;
            float4 acc[8];
            #pragma unroll
            for (int bb = 0; bb < 8; bb++) acc[bb] = make_float4(0.f, 0.f, 0.f, 0.f);
            for (int k = 0; k < 32; k++) {
                float4 w0 = *(const float4*)(W0 + k * D);
                float4 w1 = *(const float4*)(W1 + k * D);
                float4 a0 = *(const float4*)&xs0[k * 8];
                float4 a1 = *(const float4*)&xs0[k * 8 + 4];
                float4 b0 = *(const float4*)&xs1[k * 8];
                float4 b1 = *(const float4*)&xs1[k * 8 + 4];
                fma4(acc[0], a0.x, w0); fma4(acc[1], a0.y, w0);
                fma4(acc[2], a0.z, w0); fma4(acc[3], a0.w, w0);
                fma4(acc[4], a1.x, w0); fma4(acc[5], a1.y, w0);
                fma4(acc[6], a1.z, w0); fma4(acc[7], a1.w, w0);
                fma4(acc[0], b0.x, w1); fma4(acc[1], b0.y, w1);
                fma4(acc[2], b0.z, w1); fma4(acc[3], b0.w, w1);
                fma4(acc[4], b1.x, w1); fma4(acc[5], b1.y, w1);
                fma4(acc[6], b1.z, w1); fma4(acc[7], b1.w, w1);
            }
            #pragma unroll
            for (int bb = 0; bb < 8; bb++)
                *(float4*)&ws[OFF_ARENA + kc * 73728 + (i * 32 + bg * 8 + bb) * 768 + e4] = acc[bb];
        }
        __syncthreads();
    }
    grid.sync();

    // ---- P8: reduce agg partials + bv (72 vb) ----
    for (int vb = blockIdx.x; vb < 72; vb += NB) {
        int idx = vb * 256 + tid;
        int fidx = idx * 4;
        int i = fidx / 24576, e = fidx % 768;
        int j0 = (i == 0) ? 1 : 0, j1 = (i == 2) ? 1 : 2;
        float4 b0 = *(const float4*)&p.bv[j0 * 768 + e];
        float4 b1 = *(const float4*)&p.bv[j1 * 768 + e];
        float4 a = make_float4(b0.x + b1.x, b0.y + b1.y, b0.z + b1.z, b0.w + b1.w);
        #pragma unroll
        for (int kc = 0; kc < 24; kc++) {
            float4 q = *(const float4*)&ws[OFF_ARENA + kc * 73728 + fidx];
            a.x += q.x; a.y += q.y; a.z += q.z; a.w += q.w;
        }
        *(float4*)&ws[OFF_AGG + fidx] = a;
    }
    grid.sync();

    // ---- P9: E/G partials (288 vb: kind 2, i 3, bg 4, kc 12 (64 k)) ----
    for (int vb = blockIdx.x; vb < 288; vb += NB) {
        int kind = vb / 144, r = vb % 144;
        int i = r / 48, r2 = r % 48, bg = r2 / 12, kc = r2 % 12;
        int kbase = kc * 64;
        float* xa = (float*)shraw;   // [64][8]
        float* xq = xa + 512;
        for (int idx = tid; idx < 512; idx += 256) {
            int d = idx / 8, bb = idx % 8;
            xa[d * 8 + bb] = ws[OFF_AGG + (i * B + bg * 8 + bb) * D + kbase + d];
            if (kind) xq[d * 8 + bb] = ws[OFF_Q + (i * B + bg * 8 + bb) * D + kbase + d];
        }
        __syncthreads();
        if (tid < 192) {
            int e4 = tid * 4;
            float4 acc[8];
            #pragma unroll
            for (int bb = 0; bb < 8; bb++) acc[bb] = make_float4(0.f, 0.f, 0.f, 0.f);
            if (kind == 0) {
                const float* Wm = p.WE_w + i * D * D + kbase * D + e4;
                for (int k = 0; k < 64; k++) {
                    float4 w = *(const float4*)(Wm + k * D);
                    float4 a0 = *(const float4*)&xa[k * 8];
                    float4 a1 = *(const float4*)&xa[k * 8 + 4];
                    fma4(acc[0], a0.x, w); fma4(acc[1], a0.y, w);
                    fma4(acc[2], a0.z, w); fma4(acc[3], a0.w, w);
                    fma4(acc[4], a1.x, w); fma4(acc[5], a1.y, w);
                    fma4(acc[6], a1.z, w); fma4(acc[7], a1.w, w);
                }
            } else {
                const float* Wh = p.Wh_w + i * D * D + kbase * D + e4;
                const float* Wc = p.Wqc_w + i * D * D + kbase * D + e4;
                for (int k = 0; k < 64; k++) {
                    float4 wh = *(const float4*)(Wh + k * D);
                    float4 wc = *(const float4*)(Wc + k * D);
                    float4 a0 = *(const float4*)&xa[k * 8];
                    float4 a1 = *(const float4*)&xa[k * 8 + 4];
                    float4 q0 = *(const float4*)&xq[k * 8];
                    float4 q1 = *(const float4*)&xq[k * 8 + 4];
                    fma4(acc[0], a0.x, wh); fma4(acc[1], a0.y, wh);
                    fma4(acc[2], a0.z, wh); fma4(acc[3], a0.w, wh);
                    fma4(acc[4], a1.x, wh); fma4(acc[5], a1.y, wh);
                    fma4(acc[6], a1.z, wh); fma4(acc[7], a1.w, wh);
                    fma4(acc[0], q0.x, wc); fma4(acc[1], q0.y, wc);
                    fma4(acc[2], q0.z, wc); fma4(acc[3], q0.w, wc);
                    fma4(acc[4], q1.x, wc); fma4(acc[5], q1.y, wc);
                    fma4(acc[6], q1.z, wc); fma4(acc[7], q1.w, wc);
                }
            }
            int base = OFF_ARENA + (kind ? 884736 : 0) + kc * 73728;
            #pragma unroll
            for (int bb = 0; bb < 8; bb++)
                *(float4*)&ws[base + (i * 32 + bg * 8 + bb) * 768 + e4] = acc[bb];
        }
        __syncthreads();
    }
    grid.sync();

    // ---- P10: reduce E/G + bias + relu (144 vb) ----
    for (int vb = blockIdx.x; vb < 144; vb += NB) {
        bool isG = vb >= 72;
        int idx = (isG ? vb - 72 : vb) * 256 + tid;
        int fidx = idx * 4;
        int i = fidx / 24576, e = fidx % 768;
        float4 a;
        const float* base = ws + OFF_ARENA + (isG ? 884736 : 0);
        if (isG) {
            float4 b0 = *(const float4*)&p.Wh_b[i * 768 + e];
            float4 b1 = *(const float4*)&p.Wqc_b[i * 768 + e];
            a = make_float4(b0.x + b1.x, b0.y + b1.y, b0.z + b1.z, b0.w + b1.w);
        } else {
            a = *(const float4*)&p.WE_b[i * 768 + e];
        }
        #pragma unroll
        for (int kc = 0; kc < 12; kc++) {
            float4 q = *(const float4*)&base[kc * 73728 + fidx];
            a.x += q.x; a.y += q.y; a.z += q.z; a.w += q.w;
        }
        a.x = fmaxf(a.x, 0.f); a.y = fmaxf(a.y, 0.f); a.z = fmaxf(a.z, 0.f); a.w = fmaxf(a.w, 0.f);
        *(float4*)&ws[(isG ? OFF_G : OFF_E) + fidx] = a;
    }
    grid.sync();

    // ---- P11: LN(E)*LN(G) -> fused (96 vb: i,b) ----
    for (int vb = blockIdx.x; vb < 96; vb += NB) {
        int i = vb / B, b = vb % B;
        const float* E = ws + OFF_E + (i * B + b) * D;
        const float* G = ws + OFF_G + (i * B + b) * D;
        int t = tid;
        float e0 = E[t], e1 = E[t + 256], e2 = E[t + 512];
        float g0 = G[t], g1 = G[t + 256], g2 = G[t + 512];
        float* r1 = (float*)shraw;
        float* r2 = r1 + 256; float* r3 = r2 + 256; float* r4 = r3 + 256;
        r1[t] = e0 + e1 + e2;
        r2[t] = e0 * e0 + e1 * e1 + e2 * e2;
        r3[t] = g0 + g1 + g2;
        r4[t] = g0 * g0 + g1 * g1 + g2 * g2;
        __syncthreads();
        for (int st = 128; st > 0; st >>= 1) {
            if (t < st) { r1[t] += r1[t + st]; r2[t] += r2[t + st]; r3[t] += r3[t + st]; r4[t] += r4[t + st]; }
            __syncthreads();
        }
        float mE = r1[0] * (1.0f / D), vE = r2[0] * (1.0f / D) - mE * mE;
        float mG = r3[0] * (1.0f / D), vG = r4[0] * (1.0f / D) - mG * mG;
        float sE = rsqrtf(vE + LN_EPS), sG = rsqrtf(vG + LN_EPS);
        float* o = ws + OFF_FUSED + b * MD + i * D;
        const float* eg = p.lnE_g + i * D; const float* ebv = p.lnE_b + i * D;
        const float* gg = p.lnG_g + i * D; const float* gbv = p.lnG_b + i * D;
        o[t]       = ((e0 - mE) * sE * eg[t]       + ebv[t])       * ((g0 - mG) * sG * gg[t]       + gbv[t]);
        o[t + 256] = ((e1 - mE) * sE * eg[t + 256] + ebv[t + 256]) * ((g1 - mG) * sG * gg[t + 256] + gbv[t + 256]);
        o[t + 512] = ((e2 - mE) * sE * eg[t + 512] + ebv[t + 512]) * ((g2 - mG) * sG * gg[t + 512] + gbv[t + 512]);
        __syncthreads();
    }
    grid.sync();

    // ---- P12: out partials (144 vb: bg 4 (8 b), kc 36 (64 f)) ----
    for (int vb = blockIdx.x; vb < 144; vb += NB) {
        int bg = vb / 36, kc = vb % 36;
        int kbase = kc * 64;
        float* xs = (float*)shraw;   // [64][8]
        for (int idx = tid; idx < 512; idx += 256) {
            int d = idx / 8, bb = idx % 8;
            xs[d * 8 + bb] = ws[OFF_FUSED + (bg * 8 + bb) * MD + kbase + d];
        }
        __syncthreads();
        int e4 = tid * 4;
        const float* Wm = p.out_w + kbase * H + e4;
        float4 acc[8];
        #pragma unroll
        for (int bb = 0; bb < 8; bb++) acc[bb] = make_float4(0.f, 0.f, 0.f, 0.f);
        for (int k = 0; k < 64; k++) {
            float4 w = *(const float4*)(Wm + k * H);
            float4 x0 = *(const float4*)&xs[k * 8];
            float4 x1 = *(const float4*)&xs[k * 8 + 4];
            fma4(acc[0], x0.x, w); fma4(acc[1], x0.y, w);
            fma4(acc[2], x0.z, w); fma4(acc[3], x0.w, w);
            fma4(acc[4], x1.x, w); fma4(acc[5], x1.y, w);
            fma4(acc[6], x1.z, w); fma4(acc[7], x1.w, w);
        }
        #pragma unroll
        for (int bb = 0; bb < 8; bb++)
            *(float4*)&ws[OFF_ARENA + kc * 32768 + (bg * 8 + bb) * 1024 + e4] = acc[bb];
        __syncthreads();
    }
    grid.sync();

    // ---- P13: final reduce + bias, kl (32 vb: b) ----
    for (int vb = blockIdx.x; vb < 32; vb += NB) {
        int b = vb;
        int h4 = tid * 4;
        float4 a = *(const float4*)&p.out_b[h4];
        #pragma unroll
        for (int kc = 0; kc < 36; kc++) {
            float4 q = *(const float4*)&ws[OFF_ARENA + kc * 32768 + b * 1024 + h4];
            a.x += q.x; a.y += q.y; a.z += q.z; a.w += q.w;
        }
        *(float4*)&p.out[b * H + h4] = a;
        if (b == 0 && tid == 0) p.out[B * H] = ws[OFF_KL];
    }
}

// ==================== fallback: R5 multi-kernel path (known-good) ====================

__global__ __launch_bounds__(256) void k_prep(const float* Wq, const float* Wk,
        const float* bq, const float* bk,
        const float* mu_w, const float* mu_b, const float* lv_w, const float* lv_b,
        const float* pgq_w, const float* pgq_b, const float* pgk_w, const float* pgk_b,
        float* ws) {
    int blk = blockIdx.x;
    if (blk < 72) {
        int mat = blk / 12, rg = blk % 12;
        const float* Wm; const float *va, *vb, *vc;
        float *oa, *ob, *oc; int nv;
        if (mat < 3) {
            int i = mat;
            Wm = Wq + i * D * D;
            va = mu_w + i * D; vb = lv_w + i * D; vc = pgq_w + i * D;
            oa = ws + OFF_WMU + i * D; ob = ws + OFF_WLV + i * D; oc = ws + OFF_WPGQ + i * D;
            nv = 3;
        } else {
            int j = mat - 3;
            int i1 = (j == 0) ? 1 : 0, i2 = (j == 2) ? 1 : 2;
            int p1 = 2 * i1 + ((j < i1) ? j : j - 1);
            int p2 = 2 * i2 + ((j < i2) ? j : j - 1);
            Wm = Wk + j * D * D;
            va = pgk_w + i1 * D; vb = pgk_w + i2 * D; vc = va;
            oa = ws + OFF_WPK + p1 * D; ob = ws + OFF_WPK + p2 * D; oc = oa;
            nv = 2;
        }
        int wave = threadIdx.x >> 6, lane = threadIdx.x & 63;
        const float4* va4 = (const float4*)va;
        const float4* vb4 = (const float4*)vb;
        const float4* vc4 = (const float4*)vc;
        float4 A0 = va4[lane], A1 = va4[lane + 64], A2 = va4[lane + 128];
        float4 B0 = vb4[lane], B1 = vb4[lane + 64], B2 = vb4[lane + 128];
        float4 C0 = vc4[lane], C1 = vc4[lane + 64], C2 = vc4[lane + 128];
        int base = rg * 64 + wave * 16;
        for (int r = 0; r < 16; r += 2) {
            const float4* rowP = (const float4*)(Wm + (base + r) * D);
            const float4* rowQ = (const float4*)(Wm + (base + r + 1) * D);
            float4 x0 = rowP[lane], x1 = rowP[lane + 64], x2 = rowP[lane + 128];
            float4 y0 = rowQ[lane], y1 = rowQ[lane + 64], y2 = rowQ[lane + 128];
            float daP = dot4(x0, A0) + dot4(x1, A1) + dot4(x2, A2);
            float dbP = dot4(x0, B0) + dot4(x1, B1) + dot4(x2, B2);
            float dcP = dot4(x0, C0) + dot4(x1, C1) + dot4(x2, C2);
            float daQ = dot4(y0, A0) + dot4(y1, A1) + dot4(y2, A2);
            float dbQ = dot4(y0, B0) + dot4(y1, B1) + dot4(y2, B2);
            float dcQ = dot4(y0, C0) + dot4(y1, C1) + dot4(y2, C2);
            daP = wave_reduce(daP); dbP = wave_reduce(dbP);
            daQ = wave_reduce(daQ); dbQ = wave_reduce(dbQ);
            if (nv == 3) { dcP = wave_reduce(dcP); dcQ = wave_reduce(dcQ); }
            if (lane == 0) {
                oa[base + r] = daP; ob[base + r] = dbP;
                oa[base + r + 1] = daQ; ob[base + r + 1] = dbQ;
                if (nv == 3) { oc[base + r] = dcP; oc[base + r + 1] = dcQ; }
            }
        }
    } else if (blk < 87) {
        int job = blk - 72;
        const float *a, *bvec; float bias; float* out;
        if (job < 3)      { int i = job;     a = bq + i * D; bvec = mu_w + i * D;  bias = mu_b[i];  out = ws + OFF_CMU + i; }
        else if (job < 6) { int i = job - 3; a = bq + i * D; bvec = lv_w + i * D;  bias = lv_b[i];  out = ws + OFF_CLV + i; }
        else if (job < 9) { int i = job - 6; a = bq + i * D; bvec = pgq_w + i * D; bias = pgq_b[i]; out = ws + OFF_CPGQ + i; }
        else {
            int p = job - 9, i = p / 2, c = p % 2, j = c + (c >= i ? 1 : 0);
            a = bk + j * D; bvec = pgk_w + i * D; bias = pgk_b[i]; out = ws + OFF_CPK + p;
        }
        int t = threadIdx.x;
        float part = 0.f;
        if (t < 192) part = dot4(((const float4*)a)[t], ((const float4*)bvec)[t]);
        part = wave_reduce(part);
        __shared__ float r[4];
        if ((t & 63) == 0) r[t >> 6] = part;
        __syncthreads();
        if (t == 0) *out = r[0] + r[1] + r[2] + r[3] + bias;
    } else {
        int r = blk - 87;
        int j = r / 144; r = r % 144;
        int d0 = (r / 12) * 64, e0 = (r % 12) * 64;
        __shared__ float tile[64][65];
        const float* src = Wk + j * D * D;
        for (int idx = threadIdx.x; idx < 4096; idx += 256) {
            int rr = idx / 64, cc = idx % 64;
            tile[rr][cc] = src[(d0 + rr) * D + e0 + cc];
        }
        __syncthreads();
        float* dst = ws + OFF_WKT + j * D * D;
        for (int idx = threadIdx.x; idx < 4096; idx += 256) {
            int rr = idx / 64, cc = idx % 64;
            dst[(e0 + rr) * D + d0 + cc] = tile[cc][rr];
        }
    }
}

__global__ __launch_bounds__(256) void k_stats(const float* feats, float* ws) {
    __shared__ float klred[4];
    int wave = threadIdx.x >> 6, lane = threadIdx.x & 63;
    int m = blockIdx.x / 512;
    int row0 = blockIdx.x * 16 + wave * 4;
    int i1 = (m == 0) ? 1 : 0, i2 = (m == 2) ? 1 : 2;
    int p0 = 2 * i1 + ((m < i1) ? m : m - 1);
    int p1 = 2 * i2 + ((m < i2) ? m : m - 1);
    const float4* wmu  = (const float4*)(ws + OFF_WMU + m * D);
    const float4* wlv  = (const float4*)(ws + OFF_WLV + m * D);
    const float4* wpgq = (const float4*)(ws + OFF_WPGQ + m * D);
    const float4* wpk0 = (const float4*)(ws + OFF_WPK + p0 * D);
    const float4* wpk1 = (const float4*)(ws + OFF_WPK + p1 * D);
    float4 U0 = wmu[lane],  U1 = wmu[lane + 64],  U2 = wmu[lane + 128];
    float4 L0 = wlv[lane],  L1 = wlv[lane + 64],  L2 = wlv[lane + 128];
    float4 Q0 = wpgq[lane], Q1 = wpgq[lane + 64], Q2 = wpgq[lane + 128];
    float4 P0 = wpk0[lane], P1 = wpk0[lane + 64], P2 = wpk0[lane + 128];
    float4 R0 = wpk1[lane], R1 = wpk1[lane + 64], R2 = wpk1[lane + 128];
    float4 x[4][3];
    #pragma unroll
    for (int rr = 0; rr < 4; rr++) {
        const float4* f = (const float4*)(feats + (size_t)(row0 + rr) * D);
        x[rr][0] = f[lane]; x[rr][1] = f[lane + 64]; x[rr][2] = f[lane + 128];
    }
    float amu[4], alv[4], apgq[4], apk0[4], apk1[4];
    #pragma unroll
    for (int rr = 0; rr < 4; rr++) {
        amu[rr]  = dot4(x[rr][0], U0) + dot4(x[rr][1], U1) + dot4(x[rr][2], U2);
        alv[rr]  = dot4(x[rr][0], L0) + dot4(x[rr][1], L1) + dot4(x[rr][2], L2);
        apgq[rr] = dot4(x[rr][0], Q0) + dot4(x[rr][1], Q1) + dot4(x[rr][2], Q2);
        apk0[rr] = dot4(x[rr][0], P0) + dot4(x[rr][1], P1) + dot4(x[rr][2], P2);
        apk1[rr] = dot4(x[rr][0], R0) + dot4(x[rr][1], R1) + dot4(x[rr][2], R2);
    }
    #pragma unroll
    for (int rr = 0; rr < 4; rr++) {
        amu[rr] = wave_reduce(amu[rr]);  alv[rr] = wave_reduce(alv[rr]);
        apgq[rr] = wave_reduce(apgq[rr]);
        apk0[rr] = wave_reduce(apk0[rr]); apk1[rr] = wave_reduce(apk1[rr]);
    }
    if (lane == 0) {
        float cmu = ws[OFF_CMU + m], clv = ws[OFF_CLV + m];
        float cpgq = ws[OFF_CPGQ + m];
        float cpk0 = ws[OFF_CPK + p0], cpk1 = ws[OFF_CPK + p1];
        float klsum = 0.f;
        #pragma unroll
        for (int rr = 0; rr < 4; rr++) {
            int row = row0 + rr;
            int rem = row % (B * S);
            int b = rem / S, s = rem % S;
            float muv = amu[rr] + cmu;
            float lvv = alv[rr] + clv;
            ws[OFF_MU + row] = muv;
            ws[OFF_LV + row] = lvv;
            ws[OFF_PKPRE + (p0 * B + b) * S + s] = apk0[rr] + cpk0;
            ws[OFF_PKPRE + (p1 * B + b) * S + s] = apk1[rr] + cpk1;
            if (s == 0) ws[OFF_PQPRE + m * B + b] = apgq[rr] + cpgq;
            klsum += 1.0f + lvv - muv * muv - __expf(lvv);
        }
        klred[wave] = klsum;
    }
    __syncthreads();
    if (threadIdx.x == 0)
        atomicAdd(ws + OFF_KL, -(klred[0] + klred[1] + klred[2] + klred[3]));
}

__global__ __launch_bounds__(192) void k_qrow(const float* feats, const float* Wq, float* ws) {
    int blk = blockIdx.x;
    int i = blk / 96, r = blk % 96, bg = r / 24, kc = r % 24;
    int kbase = kc * 32;
    __shared__ __align__(16) float xs[32][8];
    for (int idx = threadIdx.x; idx < 256; idx += 192) {
        int d = idx / 8, bb = idx % 8;
        xs[d][bb] = feats[((size_t)(i * B + bg * 8 + bb) * S) * D + kbase + d];
    }
    __syncthreads();
    int e4 = threadIdx.x * 4;
    const float* Wm = Wq + i * D * D + kbase * D + e4;
    float4 acc[8];
    #pragma unroll
    for (int bb = 0; bb < 8; bb++) acc[bb] = make_float4(0.f, 0.f, 0.f, 0.f);
    for (int k = 0; k < 32; k++) {
        float4 w = *(const float4*)(Wm + k * D);
        float4 x0 = *(const float4*)&xs[k][0];
        float4 x1 = *(const float4*)&xs[k][4];
        fma4(acc[0], x0.x, w); fma4(acc[1], x0.y, w);
        fma4(acc[2], x0.z, w); fma4(acc[3], x0.w, w);
        fma4(acc[4], x1.x, w); fma4(acc[5], x1.y, w);
        fma4(acc[6], x1.z, w); fma4(acc[7], x1.w, w);
    }
    #pragma unroll
    for (int bb = 0; bb < 8; bb++)
        *(float4*)&ws[OFF_ARENA + kc * 73728 + (i * 32 + bg * 8 + bb) * 768 + e4] = acc[bb];
}

__global__ __launch_bounds__(256) void k_red_q(const float* bq, const float* bk, float* ws) {
    int blk = blockIdx.x;
    int i = blk / B, b = blk % B;
    int fbase = (i * B + b) * D;
    int t = threadIdx.x;
    __shared__ float4 qsh[192];
    __shared__ float redsh[8];
    if (t < 192) {
        float4 a = *(const float4*)&bq[i * D + t * 4];
        #pragma unroll
        for (int kc = 0; kc < 24; kc++) {
            float4 v = *(const float4*)&ws[OFF_ARENA + kc * 73728 + fbase + t * 4];
            a.x += v.x; a.y += v.y; a.z += v.z; a.w += v.w;
        }
        *(float4*)&ws[OFF_Q + fbase + t * 4] = a;
        qsh[t] = a;
    }
    __syncthreads();
    int jA = (i == 0) ? 1 : 0, jB = (i == 2) ? 1 : 2;
    float pA_ = 0.f, pB_ = 0.f;
    if (t < 192) {
        float4 q = qsh[t];
        pA_ = dot4(q, *(const float4*)&bk[jA * D + t * 4]);
        pB_ = dot4(q, *(const float4*)&bk[jB * D + t * 4]);
    }
    pA_ = wave_reduce(pA_); pB_ = wave_reduce(pB_);
    int wave = t >> 6, lane = t & 63;
    if (lane == 0) { redsh[wave] = pA_; redsh[4 + wave] = pB_; }
    __syncthreads();
    if (t == 0) {
        ws[OFF_QBK + (2 * i) * B + b]     = redsh[0] + redsh[1] + redsh[2] + redsh[3];
        ws[OFF_QBK + (2 * i + 1) * B + b] = redsh[4] + redsh[5] + redsh[6] + redsh[7];
    }
}

__global__ __launch_bounds__(192) void k_qk(float* ws) {
    int blk = blockIdx.x;
    int j = blk / 96, r = blk % 96, vg = r / 12, kc = r % 12;
    int kbase = kc * 64;
    int i1 = (j == 0) ? 1 : 0, i2 = (j == 2) ? 1 : 2;
    __shared__ __align__(16) float xs[64][8];
    for (int idx = threadIdx.x; idx < 512; idx += 192) {
        int d = idx / 8, v = idx % 8;
        int v64 = vg * 8 + v;
        int i_ = (v64 < 32) ? i1 : i2, b = v64 & 31;
        xs[d][v] = ws[OFF_Q + (i_ * 32 + b) * 768 + kbase + d];
    }
    __syncthreads();
    int e4 = threadIdx.x * 4;
    const float* Wm = ws + OFF_WKT + j * D * D + kbase * D + e4;
    float4 acc[8];
    #pragma unroll
    for (int bb = 0; bb < 8; bb++) acc[bb] = make_float4(0.f, 0.f, 0.f, 0.f);
    for (int k = 0; k < 64; k++) {
        float4 w = *(const float4*)(Wm + k * D);
        float4 x0 = *(const float4*)&xs[k][0];
        float4 x1 = *(const float4*)&xs[k][4];
        fma4(acc[0], x0.x, w); fma4(acc[1], x0.y, w);
        fma4(acc[2], x0.z, w); fma4(acc[3], x0.w, w);
        fma4(acc[4], x1.x, w); fma4(acc[5], x1.y, w);
        fma4(acc[6], x1.z, w); fma4(acc[7], x1.w, w);
    }
    #pragma unroll
    for (int v = 0; v < 8; v++)
        *(float4*)&ws[OFF_ARENA + kc * 147456 + (j * 64 + vg * 8 + v) * 768 + e4] = acc[v];
}

__global__ __launch_bounds__(256) void k_red_qk(float* ws) {
    int idx = blockIdx.x * 256 + threadIdx.x;
    int fidx = idx * 4;
    int p = fidx / 24576, rem = fidx % 24576;
    int b = rem / 768, d = rem % 768;
    int i = p / 2, c = p % 2, j = c + (c >= i ? 1 : 0);
    int i1 = (j == 0) ? 1 : 0;
    int iidx = (i == i1) ? 0 : 1;
    int vg = iidx * 32 + b;
    float4 a = make_float4(0.f, 0.f, 0.f, 0.f);
    #pragma unroll
    for (int kc = 0; kc < 12; kc++) {
        float4 pp = *(const float4*)&ws[OFF_ARENA + kc * 147456 + (j * 64 + vg) * 768 + d];
        a.x += pp.x; a.y += pp.y; a.z += pp.z; a.w += pp.w;
    }
    *(float4*)&ws[OFF_QK + fidx] = a;
}

__global__ __launch_bounds__(256) void k_score(const float* feats, float* ws) {
    int blk = blockIdx.x;
    int j = blk / 128, r = blk % 128, b = r / 4, kc = r % 4;
    int i1 = (j == 0) ? 1 : 0, i2 = (j == 2) ? 1 : 2;
    int pA = 2 * i1 + ((j < i1) ? j : j - 1);
    int pB = 2 * i2 + ((j < i2) ? j : j - 1);
    int wave = threadIdx.x >> 6, lane = threadIdx.x & 63;
    const float4* qa4 = (const float4*)(ws + OFF_QK + (pA * B + b) * D);
    const float4* qb4 = (const float4*)(ws + OFF_QK + (pB * B + b) * D);
    float4 qA0 = qa4[lane], qA1 = qa4[lane + 64], qA2 = qa4[lane + 128];
    float4 qB0 = qb4[lane], qB1 = qb4[lane + 64], qB2 = qb4[lane + 128];
    const float* fbase = feats + ((j * B + b) * S) * D;
    float* scA = ws + OFF_ARENA + ((j * B + b) * 2) * S;
    float* scB = scA + S;
    int k0 = kc * 64 + wave * 16;
    for (int k = k0; k < k0 + 16; k += 4) {
        float4 x[4][3];
        #pragma unroll
        for (int rr = 0; rr < 4; rr++) {
            const float4* f = (const float4*)(fbase + (k + rr) * D);
            x[rr][0] = f[lane]; x[rr][1] = f[lane + 64]; x[rr][2] = f[lane + 128];
        }
        float dA[4], dB[4];
        #pragma unroll
        for (int rr = 0; rr < 4; rr++) {
            dA[rr] = dot4(x[rr][0], qA0) + dot4(x[rr][1], qA1) + dot4(x[rr][2], qA2);
            dB[rr] = dot4(x[rr][0], qB0) + dot4(x[rr][1], qB1) + dot4(x[rr][2], qB2);
        }
        #pragma unroll
        for (int rr = 0; rr < 4; rr++) { dA[rr] = wave_reduce(dA[rr]); dB[rr] = wave_reduce(dB[rr]); }
        if (lane == 0) {
            #pragma unroll
            for (int rr = 0; rr < 4; rr++) { scA[k + rr] = dA[rr]; scB[k + rr] = dB[rr]; }
        }
    }
}

__global__ __launch_bounds__(256) void k_wsum(const float* feats, const float* eps,
                                              const float* dyn, float* ws) {
    int blk = blockIdx.x;
    int j = blk / 96, r = blk % 96, b = r / 3, dc = r % 3;
    int i1 = (j == 0) ? 1 : 0, i2 = (j == 2) ? 1 : 2;
    int pA = 2 * i1 + ((j < i1) ? j : j - 1);
    int pB = 2 * i2 + ((j < i2) ? j : j - 1);
    __shared__ float sA[S], sB[S], redm[256];
    int t = threadIdx.x;
    float dynv = dyn[0];
    const float* rawA = ws + OFF_ARENA + ((j * B + b) * 2) * S;
    const float* rawB = rawA + S;
    {
        float muk = ws[OFF_MU + (i1 * B + b) * S + t];
        float lvk = ws[OFF_LV + (i1 * B + b) * S + t];
        float ek  = eps[(pA * B + b) * S + t];
        float g   = sigmoidf(muk + dynv * __expf(0.5f * lvk) * ek);
        float pk  = sigmoidf(ws[OFF_PKPRE + (pA * B + b) * S + t]) * g;
        float mu0 = ws[OFF_MU + (i1 * B + b) * S];
        float lv0 = ws[OFF_LV + (i1 * B + b) * S];
        float e0  = eps[(pA * B + b) * S];
        float g0  = sigmoidf(mu0 + dynv * __expf(0.5f * lv0) * e0);
        float pq  = sigmoidf(ws[OFF_PQPRE + i1 * B + b]) * g0;
        float qbk = ws[OFF_QBK + pA * B + b];
        sA[t] = (rawA[t] + qbk) * SCALE * pq * pk;
        muk = ws[OFF_MU + (i2 * B + b) * S + t];
        lvk = ws[OFF_LV + (i2 * B + b) * S + t];
        ek  = eps[(pB * B + b) * S + t];
        g   = sigmoidf(muk + dynv * __expf(0.5f * lvk) * ek);
        pk  = sigmoidf(ws[OFF_PKPRE + (pB * B + b) * S + t]) * g;
        mu0 = ws[OFF_MU + (i2 * B + b) * S];
        lv0 = ws[OFF_LV + (i2 * B + b) * S];
        e0  = eps[(pB * B + b) * S];
        g0  = sigmoidf(mu0 + dynv * __expf(0.5f * lv0) * e0);
        pq  = sigmoidf(ws[OFF_PQPRE + i2 * B + b]) * g0;
        qbk = ws[OFF_QBK + pB * B + b];
        sB[t] = (rawB[t] + qbk) * SCALE * pq * pk;
    }
    __syncthreads();
    redm[t] = sA[t]; __syncthreads();
    for (int st = 128; st > 0; st >>= 1) { if (t < st) redm[t] = fmaxf(redm[t], redm[t + st]); __syncthreads(); }
    float mxA = redm[0]; __syncthreads();
    float wA = __expf(sA[t] - mxA);
    redm[t] = wA; __syncthreads();
    for (int st = 128; st > 0; st >>= 1) { if (t < st) redm[t] += redm[t + st]; __syncthreads(); }
    float sumA = redm[0]; __syncthreads();
    sA[t] = wA / sumA;
    __syncthreads();
    redm[t] = sB[t]; __syncthreads();
    for (int st = 128; st > 0; st >>= 1) { if (t < st) redm[t] = fmaxf(redm[t], redm[t + st]); __syncthreads(); }
    float mxB = redm[0]; __syncthreads();
    float wB = __expf(sB[t] - mxB);
    redm[t] = wB; __syncthreads();
    for (int st = 128; st > 0; st >>= 1) { if (t < st) redm[t] += redm[t + st]; __syncthreads(); }
    float sumB = redm[0]; __syncthreads();
    sB[t] = wB / sumB;
    __syncthreads();
    int dim = dc * 256 + t;
    const float* fcol = feats + ((j * B + b) * S) * D + dim;
    float accA = 0.f, accB = 0.f;
    #pragma unroll 8
    for (int k = 0; k < S; k++) {
        float fv = fcol[k * D];
        accA += sA[k] * fv;
        accB += sB[k] * fv;
    }
    ws[OFF_FSUM + (pA * B + b) * D + dim] = accA;
    ws[OFF_FSUM + (pB * B + b) * D + dim] = accB;
}

__global__ __launch_bounds__(192) void k_agg(const float* Wv, float* ws) {
    int blk = blockIdx.x;
    int i = blk / 96, r = blk % 96, bg = r / 24, kc = r % 24;
    int kbase = kc * 32;
    int j0 = (i == 0) ? 1 : 0, j1 = (i == 2) ? 1 : 2;
    int p0 = 2 * i, p1 = 2 * i + 1;
    __shared__ __align__(16) float xs0[32][8], xs1[32][8];
    for (int idx = threadIdx.x; idx < 256; idx += 192) {
        int d = idx / 8, bb = idx % 8;
        xs0[d][bb] = ws[OFF_FSUM + (p0 * B + bg * 8 + bb) * D + kbase + d];
        xs1[d][bb] = ws[OFF_FSUM + (p1 * B + bg * 8 + bb) * D + kbase + d];
    }
    __syncthreads();
    int e4 = threadIdx.x * 4;
    const float* W0 = Wv + j0 * D * D + kbase * D + e4;
    const float* W1 = Wv + j1 * D * D + kbase * D + e4;
    float4 acc[8];
    #pragma unroll
    for (int bb = 0; bb < 8; bb++) acc[bb] = make_float4(0.f, 0.f, 0.f, 0.f);
    for (int k = 0; k < 32; k++) {
        float4 w0 = *(const float4*)(W0 + k * D);
        float4 w1 = *(const float4*)(W1 + k * D);
        float4 a0 = *(const float4*)&xs0[k][0];
        float4 a1 = *(const float4*)&xs0[k][4];
        float4 b0 = *(const float4*)&xs1[k][0];
        float4 b1 = *(const float4*)&xs1[k][4];
        fma4(acc[0], a0.x, w0); fma4(acc[1], a0.y, w0);
        fma4(acc[2], a0.z, w0); fma4(acc[3], a0.w, w0);
        fma4(acc[4], a1.x, w0); fma4(acc[5], a1.y, w0);
        fma4(acc[6], a1.z, w0); fma4(acc[7], a1.w, w0);
        fma4(acc[0], b0.x, w1); fma4(acc[1], b0.y, w1);
        fma4(acc[2], b0.z, w1); fma4(acc[3], b0.w, w1);
        fma4(acc[4], b1.x, w1); fma4(acc[5], b1.y, w1);
        fma4(acc[6], b1.z, w1); fma4(acc[7], b1.w, w1);
    }
    #pragma unroll
    for (int bb = 0; bb < 8; bb++)
        *(float4*)&ws[OFF_ARENA + kc * 73728 + (i * 32 + bg * 8 + bb) * 768 + e4] = acc[bb];
}

__global__ __launch_bounds__(256) void k_red_agg(const float* bv, float* ws) {
    int idx = blockIdx.x * 256 + threadIdx.x;
    int fidx = idx * 4;
    int i = fidx / 24576, e = fidx % 768;
    int j0 = (i == 0) ? 1 : 0, j1 = (i == 2) ? 1 : 2;
    float4 b0 = *(const float4*)&bv[j0 * 768 + e];
    float4 b1 = *(const float4*)&bv[j1 * 768 + e];
    float4 a = make_float4(b0.x + b1.x, b0.y + b1.y, b0.z + b1.z, b0.w + b1.w);
    const float* base = ws + OFF_ARENA;
    #pragma unroll
    for (int kc = 0; kc < 24; kc++) {
        float4 p = *(const float4*)&base[kc * 73728 + fidx];
        a.x += p.x; a.y += p.y; a.z += p.z; a.w += p.w;
    }
    *(float4*)&ws[OFF_AGG + fidx] = a;
}

__global__ __launch_bounds__(192) void k_eg(const float* WE_w, const float* Wh_w,
                                            const float* Wqc_w, float* ws) {
    int blk = blockIdx.x;
    int kind = blk / 144, r = blk % 144;
    int i = r / 48, r2 = r % 48, bg = r2 / 12, kc = r2 % 12;
    int kbase = kc * 64;
    __shared__ __align__(16) float xa[64][8], xq[64][8];
    for (int idx = threadIdx.x; idx < 512; idx += 192) {
        int d = idx / 8, bb = idx % 8;
        xa[d][bb] = ws[OFF_AGG + (i * B + bg * 8 + bb) * D + kbase + d];
        if (kind) xq[d][bb] = ws[OFF_Q + (i * B + bg * 8 + bb) * D + kbase + d];
    }
    __syncthreads();
    int e4 = threadIdx.x * 4;
    float4 acc[8];
    #pragma unroll
    for (int bb = 0; bb < 8; bb++) acc[bb] = make_float4(0.f, 0.f, 0.f, 0.f);
    if (kind == 0) {
        const float* Wm = WE_w + i * D * D + kbase * D + e4;
        for (int k = 0; k < 64; k++) {
            float4 w = *(const float4*)(Wm + k * D);
            float4 a0 = *(const float4*)&xa[k][0];
            float4 a1 = *(const float4*)&xa[k][4];
            fma4(acc[0], a0.x, w); fma4(acc[1], a0.y, w);
            fma4(acc[2], a0.z, w); fma4(acc[3], a0.w, w);
            fma4(acc[4], a1.x, w); fma4(acc[5], a1.y, w);
            fma4(acc[6], a1.z, w); fma4(acc[7], a1.w, w);
        }
    } else {
        const float* Wh = Wh_w + i * D * D + kbase * D + e4;
        const float* Wc = Wqc_w + i * D * D + kbase * D + e4;
        for (int k = 0; k < 64; k++) {
            float4 wh = *(const float4*)(Wh + k * D);
            float4 wc = *(const float4*)(Wc + k * D);
            float4 a0 = *(const float4*)&xa[k][0];
            float4 a1 = *(const float4*)&xa[k][4];
            float4 q0 = *(const float4*)&xq[k][0];
            float4 q1 = *(const float4*)&xq[k][4];
            fma4(acc[0], a0.x, wh); fma4(acc[1], a0.y, wh);
            fma4(acc[2], a0.z, wh); fma4(acc[3], a0.w, wh);
            fma4(acc[4], a1.x, wh); fma4(acc[5], a1.y, wh);
            fma4(acc[6], a1.z, wh); fma4(acc[7], a1.w, wh);
            fma4(acc[0], q0.x, wc); fma4(acc[1], q0.y, wc);
            fma4(acc[2], q0.z, wc); fma4(acc[3], q0.w, wc);
            fma4(acc[4], q1.x, wc); fma4(acc[5], q1.y, wc);
            fma4(acc[6], q1.z, wc); fma4(acc[7], q1.w, wc);
        }
    }
    int base = OFF_ARENA + (kind ? 884736 : 0) + kc * 73728;
    #pragma unroll
    for (int bb = 0; bb < 8; bb++)
        *(float4*)&ws[base + (i * 32 + bg * 8 + bb) * 768 + e4] = acc[bb];
}

__global__ __launch_bounds__(256) void k_red_eg(const float* WE_b, const float* Wh_b,
                                                const float* Wqc_b, float* ws) {
    int blk = blockIdx.x;
    bool isG = blk >= 72;
    int idx = (isG ? blk - 72 : blk) * 256 + threadIdx.x;
    int fidx = idx * 4;
    int i = fidx / 24576, e = fidx % 768;
    float4 a;
    const float* base = ws + OFF_ARENA + (isG ? 884736 : 0);
    if (isG) {
        float4 b0 = *(const float4*)&Wh_b[i * 768 + e];
        float4 b1 = *(const float4*)&Wqc_b[i * 768 + e];
        a = make_float4(b0.x + b1.x, b0.y + b1.y, b0.z + b1.z, b0.w + b1.w);
    } else {
        a = *(const float4*)&WE_b[i * 768 + e];
    }
    #pragma unroll
    for (int kc = 0; kc < 12; kc++) {
        float4 p = *(const float4*)&base[kc * 73728 + fidx];
        a.x += p.x; a.y += p.y; a.z += p.z; a.w += p.w;
    }
    a.x = fmaxf(a.x, 0.f); a.y = fmaxf(a.y, 0.f); a.z = fmaxf(a.z, 0.f); a.w = fmaxf(a.w, 0.f);
    *(float4*)&ws[(isG ? OFF_G : OFF_E) + fidx] = a;
}

__global__ __launch_bounds__(256) void k_ln(const float* lnE_g, const float* lnE_b,
        const float* lnG_g, const float* lnG_b, float* ws) {
    int blk = blockIdx.x;
    int i = blk / B, b = blk % B;
    const float* E = ws + OFF_E + (i * B + b) * D;
    const float* G = ws + OFF_G + (i * B + b) * D;
    int t = threadIdx.x;
    float e0 = E[t], e1 = E[t + 256], e2 = E[t + 512];
    float g0 = G[t], g1 = G[t + 256], g2 = G[t + 512];
    __shared__ float r1[256], r2[256], r3[256], r4[256];
    r1[t] = e0 + e1 + e2;
    r2[t] = e0 * e0 + e1 * e1 + e2 * e2;
    r3[t] = g0 + g1 + g2;
    r4[t] = g0 * g0 + g1 * g1 + g2 * g2;
    __syncthreads();
    for (int st = 128; st > 0; st >>= 1) {
        if (t < st) { r1[t] += r1[t + st]; r2[t] += r2[t + st]; r3[t] += r3[t + st]; r4[t] += r4[t + st]; }
        __syncthreads();
    }
    float mE = r1[0] * (1.0f / D), vE = r2[0] * (1.0f / D) - mE * mE;
    float mG = r3[0] * (1.0f / D), vG = r4[0] * (1.0f / D) - mG * mG;
    float sE = rsqrtf(vE + LN_EPS), sG = rsqrtf(vG + LN_EPS);
    float* o = ws + OFF_FUSED + b * MD + i * D;
    const float* eg = lnE_g + i * D; const float* ebv = lnE_b + i * D;
    const float* gg = lnG_g + i * D; const float* gbv = lnG_b + i * D;
    o[t]       = ((e0 - mE) * sE * eg[t]       + ebv[t])       * ((g0 - mG) * sG * gg[t]       + gbv[t]);
    o[t + 256] = ((e1 - mE) * sE * eg[t + 256] + ebv[t + 256]) * ((g1 - mG) * sG * gg[t + 256] + gbv[t + 256]);
    o[t + 512] = ((e2 - mE) * sE * eg[t + 512] + ebv[t + 512]) * ((g2 - mG) * sG * gg[t + 512] + gbv[t + 512]);
}

__global__ __launch_bounds__(256) void k_out(const float* out_w, float* ws) {
    int blk = blockIdx.x;
    int bg = blk / 36, kc = blk % 36;
    int kbase = kc * 64;
    __shared__ __align__(16) float xs[64][8];
    for (int idx = threadIdx.x; idx < 512; idx += 256) {
        int d = idx / 8, bb = idx % 8;
        xs[d][bb] = ws[OFF_FUSED + (bg * 8 + bb) * MD + kbase + d];
    }
    __syncthreads();
    int e4 = threadIdx.x * 4;
    const float* Wm = out_w + kbase * H + e4;
    float4 acc[8];
    #pragma unroll
    for (int bb = 0; bb < 8; bb++) acc[bb] = make_float4(0.f, 0.f, 0.f, 0.f);
    for (int k = 0; k < 64; k++) {
        float4 w = *(const float4*)(Wm + k * H);
        float4 x0 = *(const float4*)&xs[k][0];
        float4 x1 = *(const float4*)&xs[k][4];
        fma4(acc[0], x0.x, w); fma4(acc[1], x0.y, w);
        fma4(acc[2], x0.z, w); fma4(acc[3], x0.w, w);
        fma4(acc[4], x1.x, w); fma4(acc[5], x1.y, w);
        fma4(acc[6], x1.z, w); fma4(acc[7], x1.w, w);
    }
    #pragma unroll
    for (int bb = 0; bb < 8; bb++)
        *(float4*)&ws[OFF_ARENA + kc * 32768 + (bg * 8 + bb) * 1024 + e4] = acc[bb];
}

__global__ __launch_bounds__(256) void k_fin(const float* out_b, float* ws, float* out) {
    int b = blockIdx.x;
    int h4 = threadIdx.x * 4;
    float4 a = *(const float4*)&out_b[h4];
    #pragma unroll
    for (int kc = 0; kc < 36; kc++) {
        float4 p = *(const float4*)&ws[OFF_ARENA + kc * 32768 + b * 1024 + h4];
        a.x += p.x; a.y += p.y; a.z += p.z; a.w += p.w;
    }
    *(float4*)&out[b * H + h4] = a;
    if (b == 0 && threadIdx.x == 0) out[B * H] = ws[OFF_KL];
}

extern "C" void kernel_launch(void* const* d_in, const int* in_sizes, int n_in,
                              void* d_out, int out_size, void* d_ws, size_t ws_size,
                              hipStream_t stream) {
    const float* feats = (const float*)d_in[0];
    const float* Wq    = (const float*)d_in[1];
    const float* bq    = (const float*)d_in[2];
    const float* Wk    = (const float*)d_in[3];
    const float* bk    = (const float*)d_in[4];
    const float* Wv    = (const float*)d_in[5];
    const float* bv    = (const float*)d_in[6];
    const float* pgq_w = (const float*)d_in[7];
    const float* pgq_b = (const float*)d_in[8];
    const float* pgk_w = (const float*)d_in[9];
    const float* pgk_b = (const float*)d_in[10];
    const float* mu_w  = (const float*)d_in[11];
    const float* mu_b  = (const float*)d_in[12];
    const float* lv_w  = (const float*)d_in[13];
    const float* lv_b  = (const float*)d_in[14];
    const float* dyn   = (const float*)d_in[15];
    const float* WE_w  = (const float*)d_in[16];
    const float* WE_b  = (const float*)d_in[17];
    const float* Wh_w  = (const float*)d_in[18];
    const float* Wh_b  = (const float*)d_in[19];
    const float* Wqc_w = (const float*)d_in[20];
    const float* Wqc_b = (const float*)d_in[21];
    const float* lnE_g = (const float*)d_in[22];
    const float* lnE_b = (const float*)d_in[23];
    const float* lnG_g = (const float*)d_in[24];
    const float* lnG_b = (const float*)d_in[25];
    const float* out_w = (const float*)d_in[26];
    const float* out_b = (const float*)d_in[27];
    const float* eps   = (const float*)d_in[28];
    float* ws  = (float*)d_ws;
    float* out = (float*)d_out;

    MegaParams p = { feats, Wq, bq, Wk, bk, Wv, bv,
                     pgq_w, pgq_b, pgk_w, pgk_b,
                     mu_w, mu_b, lv_w, lv_b, dyn,
                     WE_w, WE_b, Wh_w, Wh_b, Wqc_w, Wqc_b,
                     lnE_g, lnE_b, lnG_g, lnG_b, out_w, out_b, eps,
                     ws, out };
    void* args[] = { &p };
    hipError_t err = hipLaunchCooperativeKernel((const void*)k_mega, dim3(512), dim3(256),
                                                args, 0, stream);
    if (err != hipSuccess) {
        // Fallback: known-good R5 multi-kernel path.
        hipMemsetAsync((char*)d_ws + OFF_KL * sizeof(float), 0, sizeof(float), stream);
        k_prep<<<519, 256, 0, stream>>>(Wq, Wk, bq, bk, mu_w, mu_b, lv_w, lv_b,
                                        pgq_w, pgq_b, pgk_w, pgk_b, ws);
        k_stats<<<1536, 256, 0, stream>>>(feats, ws);
        k_qrow<<<288, 192, 0, stream>>>(feats, Wq, ws);
        k_red_q<<<96, 256, 0, stream>>>(bq, bk, ws);
        k_qk<<<288, 192, 0, stream>>>(ws);
        k_red_qk<<<144, 256, 0, stream>>>(ws);
        k_score<<<384, 256, 0, stream>>>(feats, ws);
        k_wsum<<<288, 256, 0, stream>>>(feats, eps, dyn, ws);
        k_agg<<<288, 192, 0, stream>>>(Wv, ws);
        k_red_agg<<<72, 256, 0, stream>>>(bv, ws);
        k_eg<<<288, 192, 0, stream>>>(WE_w, Wh_w, Wqc_w, ws);
        k_red_eg<<<144, 256, 0, stream>>>(WE_b, Wh_b, Wqc_b, ws);
        k_ln<<<M * B, 256, 0, stream>>>(lnE_g, lnE_b, lnG_g, lnG_b, ws);
        k_out<<<144, 256, 0, stream>>>(out_w, ws);
        k_fin<<<32, 256, 0, stream>>>(out_b, ws, out);
    }
}

// Round 7
// 417.135 us; speedup vs baseline: 2.6012x; 2.6012x over previous
//
#include <hip/hip_runtime.h>

// Problem constants (fixed by the reference)
#define M 3
#define B 32
#define S 256
#define D 768
#define H 1024
#define MD (M * D)          // 2304
#define NP (M * (M - 1))    // 6 ordered (i,j) pairs
#define SCALE 0.03608439182435161f  // 1/sqrt(768)
#define LN_EPS 1e-5f

// Workspace layout (float offsets). Total 4312704 floats = ~17.3 MB.
#define OFF_WMU   0         // [M][D]
#define OFF_WLV   2304      // [M][D]
#define OFF_WPGQ  4608      // [M][D]
#define OFF_WPK   6912      // [NP][D]
#define OFF_CMU   11520     // [M]
#define OFF_CLV   11523     // [M]
#define OFF_CPGQ  11526     // [M]
#define OFF_CPK   11529     // [NP]
#define OFF_MU    11552     // [M][B][S]
#define OFF_LV    36128     // [M][B][S]
#define OFF_PKPRE 60704     // [NP][B][S]
#define OFF_PQPRE 109856    // [M][B]
#define OFF_Q     109952    // [M][B][D]
#define OFF_QBK   183680    // [NP][B]
#define OFF_QK    183872    // [NP][B][D]
#define OFF_FSUM  331328    // [NP][B][D]
#define OFF_AGG   478784    // [M][B][D]
#define OFF_E     552512    // [M][B][D]
#define OFF_G     626240    // [M][B][D]
#define OFF_FUSED 699968    // [B][MD]
#define OFF_KL    773696    // [1]
#define OFF_WKT   773760    // [M][D][D] Wk transposed (1769472 floats)
#define OFF_ARENA 2543232   // k-split partials / raw scores (max 1769472 floats)

__device__ __forceinline__ float wave_reduce(float v) {
    #pragma unroll
    for (int o = 32; o > 0; o >>= 1) v += __shfl_down(v, o, 64);
    return v;
}

__device__ __forceinline__ float sigmoidf(float x) {
    return 1.0f / (1.0f + __expf(-x));
}

__device__ __forceinline__ float dot4(float4 a, float4 b) {
    return a.x * b.x + a.y * b.y + a.z * b.z + a.w * b.w;
}

__device__ __forceinline__ void fma4(float4& a, float s, float4 w) {
    a.x += s * w.x; a.y += s * w.y; a.z += s * w.z; a.w += s * w.w;
}

// K0: fused prep: blocks 0..71 vector-dots, 72..86 scalar consts, 87..518 Wk transpose.
// Block 0 also zeroes the KL accumulator (consumed only by later dispatches).
__global__ __launch_bounds__(256) void k_prep(const float* Wq, const float* Wk,
        const float* bq, const float* bk,
        const float* mu_w, const float* mu_b, const float* lv_w, const float* lv_b,
        const float* pgq_w, const float* pgq_b, const float* pgk_w, const float* pgk_b,
        float* ws) {
    int blk = blockIdx.x;
    if (blk == 0 && threadIdx.x == 0) ws[OFF_KL] = 0.f;
    if (blk < 72) {
        int mat = blk / 12, rg = blk % 12;
        const float* Wm; const float *va, *vb, *vc;
        float *oa, *ob, *oc; int nv;
        if (mat < 3) {
            int i = mat;
            Wm = Wq + i * D * D;
            va = mu_w + i * D; vb = lv_w + i * D; vc = pgq_w + i * D;
            oa = ws + OFF_WMU + i * D; ob = ws + OFF_WLV + i * D; oc = ws + OFF_WPGQ + i * D;
            nv = 3;
        } else {
            int j = mat - 3;
            int i1 = (j == 0) ? 1 : 0, i2 = (j == 2) ? 1 : 2;
            int p1 = 2 * i1 + ((j < i1) ? j : j - 1);
            int p2 = 2 * i2 + ((j < i2) ? j : j - 1);
            Wm = Wk + j * D * D;
            va = pgk_w + i1 * D; vb = pgk_w + i2 * D; vc = va;
            oa = ws + OFF_WPK + p1 * D; ob = ws + OFF_WPK + p2 * D; oc = oa;
            nv = 2;
        }
        int wave = threadIdx.x >> 6, lane = threadIdx.x & 63;
        const float4* va4 = (const float4*)va;
        const float4* vb4 = (const float4*)vb;
        const float4* vc4 = (const float4*)vc;
        float4 A0 = va4[lane], A1 = va4[lane + 64], A2 = va4[lane + 128];
        float4 B0 = vb4[lane], B1 = vb4[lane + 64], B2 = vb4[lane + 128];
        float4 C0 = vc4[lane], C1 = vc4[lane + 64], C2 = vc4[lane + 128];
        int base = rg * 64 + wave * 16;
        for (int r = 0; r < 16; r += 2) {
            const float4* rowP = (const float4*)(Wm + (base + r) * D);
            const float4* rowQ = (const float4*)(Wm + (base + r + 1) * D);
            float4 x0 = rowP[lane], x1 = rowP[lane + 64], x2 = rowP[lane + 128];
            float4 y0 = rowQ[lane], y1 = rowQ[lane + 64], y2 = rowQ[lane + 128];
            float daP = dot4(x0, A0) + dot4(x1, A1) + dot4(x2, A2);
            float dbP = dot4(x0, B0) + dot4(x1, B1) + dot4(x2, B2);
            float dcP = dot4(x0, C0) + dot4(x1, C1) + dot4(x2, C2);
            float daQ = dot4(y0, A0) + dot4(y1, A1) + dot4(y2, A2);
            float dbQ = dot4(y0, B0) + dot4(y1, B1) + dot4(y2, B2);
            float dcQ = dot4(y0, C0) + dot4(y1, C1) + dot4(y2, C2);
            daP = wave_reduce(daP); dbP = wave_reduce(dbP);
            daQ = wave_reduce(daQ); dbQ = wave_reduce(dbQ);
            if (nv == 3) { dcP = wave_reduce(dcP); dcQ = wave_reduce(dcQ); }
            if (lane == 0) {
                oa[base + r] = daP; ob[base + r] = dbP;
                oa[base + r + 1] = daQ; ob[base + r + 1] = dbQ;
                if (nv == 3) { oc[base + r] = dcP; oc[base + r + 1] = dcQ; }
            }
        }
    } else if (blk < 87) {
        int job = blk - 72;
        const float *a, *bvec; float bias; float* out;
        if (job < 3)      { int i = job;     a = bq + i * D; bvec = mu_w + i * D;  bias = mu_b[i];  out = ws + OFF_CMU + i; }
        else if (job < 6) { int i = job - 3; a = bq + i * D; bvec = lv_w + i * D;  bias = lv_b[i];  out = ws + OFF_CLV + i; }
        else if (job < 9) { int i = job - 6; a = bq + i * D; bvec = pgq_w + i * D; bias = pgq_b[i]; out = ws + OFF_CPGQ + i; }
        else {
            int p = job - 9, i = p / 2, c = p % 2, j = c + (c >= i ? 1 : 0);
            a = bk + j * D; bvec = pgk_w + i * D; bias = pgk_b[i]; out = ws + OFF_CPK + p;
        }
        int t = threadIdx.x;
        float part = 0.f;
        if (t < 192) part = dot4(((const float4*)a)[t], ((const float4*)bvec)[t]);
        part = wave_reduce(part);
        __shared__ float r[4];
        if ((t & 63) == 0) r[t >> 6] = part;
        __syncthreads();
        if (t == 0) *out = r[0] + r[1] + r[2] + r[3] + bias;
    } else {
        int r = blk - 87;
        int j = r / 144; r = r % 144;
        int d0 = (r / 12) * 64, e0 = (r % 12) * 64;
        __shared__ float tile[64][65];
        const float* src = Wk + j * D * D;
        for (int idx = threadIdx.x; idx < 4096; idx += 256) {
            int rr = idx / 64, cc = idx % 64;
            tile[rr][cc] = src[(d0 + rr) * D + e0 + cc];
        }
        __syncthreads();
        float* dst = ws + OFF_WKT + j * D * D;
        for (int idx = threadIdx.x; idx < 4096; idx += 256) {
            int rr = idx / 64, cc = idx % 64;
            dst[(e0 + rr) * D + d0 + cc] = tile[cc][rr];
        }
    }
}

// K2: Q partials, 16 batch rows/block. 144 blocks (i 3, bg 2 (16 b), kc 24 (32 k)).
__global__ __launch_bounds__(192) void k_qrow(const float* feats, const float* Wq, float* ws) {
    int blk = blockIdx.x;
    int i = blk / 48, r = blk % 48, bg = r / 24, kc = r % 24;
    int kbase = kc * 32;
    __shared__ __align__(16) float xs[32][16];
    for (int idx = threadIdx.x; idx < 512; idx += 192) {
        int d = idx / 16, bb = idx % 16;
        xs[d][bb] = feats[((size_t)(i * B + bg * 16 + bb) * S) * D + kbase + d];
    }
    __syncthreads();
    int e4 = threadIdx.x * 4;
    const float* Wm = Wq + i * D * D + kbase * D + e4;
    float4 acc[16];
    #pragma unroll
    for (int bb = 0; bb < 16; bb++) acc[bb] = make_float4(0.f, 0.f, 0.f, 0.f);
    for (int k = 0; k < 32; k++) {
        float4 w = *(const float4*)(Wm + k * D);
        float4 x0 = *(const float4*)&xs[k][0];
        float4 x1 = *(const float4*)&xs[k][4];
        float4 x2 = *(const float4*)&xs[k][8];
        float4 x3 = *(const float4*)&xs[k][12];
        fma4(acc[0], x0.x, w);  fma4(acc[1], x0.y, w);
        fma4(acc[2], x0.z, w);  fma4(acc[3], x0.w, w);
        fma4(acc[4], x1.x, w);  fma4(acc[5], x1.y, w);
        fma4(acc[6], x1.z, w);  fma4(acc[7], x1.w, w);
        fma4(acc[8], x2.x, w);  fma4(acc[9], x2.y, w);
        fma4(acc[10], x2.z, w); fma4(acc[11], x2.w, w);
        fma4(acc[12], x3.x, w); fma4(acc[13], x3.y, w);
        fma4(acc[14], x3.z, w); fma4(acc[15], x3.w, w);
    }
    #pragma unroll
    for (int bb = 0; bb < 16; bb++)
        *(float4*)&ws[OFF_ARENA + kc * 73728 + (i * 32 + bg * 16 + bb) * 768 + e4] = acc[bb];
}

// reduce Q partials (24 kc) + bias; also qbk for both pairs. 96 blocks (i,b).
__global__ __launch_bounds__(256) void k_red_q(const float* bq, const float* bk, float* ws) {
    int blk = blockIdx.x;
    int i = blk / B, b = blk % B;
    int fbase = (i * B + b) * D;
    int t = threadIdx.x;
    __shared__ float4 qsh[192];
    __shared__ float redsh[8];
    if (t < 192) {
        float4 a = *(const float4*)&bq[i * D + t * 4];
        #pragma unroll
        for (int kc = 0; kc < 24; kc++) {
            float4 v = *(const float4*)&ws[OFF_ARENA + kc * 73728 + fbase + t * 4];
            a.x += v.x; a.y += v.y; a.z += v.z; a.w += v.w;
        }
        *(float4*)&ws[OFF_Q + fbase + t * 4] = a;
        qsh[t] = a;
    }
    __syncthreads();
    int jA = (i == 0) ? 1 : 0, jB = (i == 2) ? 1 : 2;
    float pA_ = 0.f, pB_ = 0.f;
    if (t < 192) {
        float4 q = qsh[t];
        pA_ = dot4(q, *(const float4*)&bk[jA * D + t * 4]);
        pB_ = dot4(q, *(const float4*)&bk[jB * D + t * 4]);
    }
    pA_ = wave_reduce(pA_); pB_ = wave_reduce(pB_);
    int wave = t >> 6, lane = t & 63;
    if (lane == 0) { redsh[wave] = pA_; redsh[4 + wave] = pB_; }
    __syncthreads();
    if (t == 0) {
        ws[OFF_QBK + (2 * i) * B + b]     = redsh[0] + redsh[1] + redsh[2] + redsh[3];
        ws[OFF_QBK + (2 * i + 1) * B + b] = redsh[4] + redsh[5] + redsh[6] + redsh[7];
    }
}

// K3: qk partials with WkT, 16 qvecs/block. 144 blocks (j 3, vg 4 (16 qvecs), kc 12 (64 k)).
__global__ __launch_bounds__(192) void k_qk(float* ws) {
    int blk = blockIdx.x;
    int j = blk / 48, r = blk % 48, vg = r / 12, kc = r % 12;
    int kbase = kc * 64;
    int i1 = (j == 0) ? 1 : 0, i2 = (j == 2) ? 1 : 2;
    __shared__ __align__(16) float xs[64][16];
    for (int idx = threadIdx.x; idx < 1024; idx += 192) {
        int d = idx / 16, v = idx % 16;
        int v64 = vg * 16 + v;
        int i_ = (v64 < 32) ? i1 : i2, b = v64 & 31;
        xs[d][v] = ws[OFF_Q + (i_ * 32 + b) * 768 + kbase + d];
    }
    __syncthreads();
    int e4 = threadIdx.x * 4;
    const float* Wm = ws + OFF_WKT + j * D * D + kbase * D + e4;
    float4 acc[16];
    #pragma unroll
    for (int bb = 0; bb < 16; bb++) acc[bb] = make_float4(0.f, 0.f, 0.f, 0.f);
    for (int k = 0; k < 64; k++) {
        float4 w = *(const float4*)(Wm + k * D);
        float4 x0 = *(const float4*)&xs[k][0];
        float4 x1 = *(const float4*)&xs[k][4];
        float4 x2 = *(const float4*)&xs[k][8];
        float4 x3 = *(const float4*)&xs[k][12];
        fma4(acc[0], x0.x, w);  fma4(acc[1], x0.y, w);
        fma4(acc[2], x0.z, w);  fma4(acc[3], x0.w, w);
        fma4(acc[4], x1.x, w);  fma4(acc[5], x1.y, w);
        fma4(acc[6], x1.z, w);  fma4(acc[7], x1.w, w);
        fma4(acc[8], x2.x, w);  fma4(acc[9], x2.y, w);
        fma4(acc[10], x2.z, w); fma4(acc[11], x2.w, w);
        fma4(acc[12], x3.x, w); fma4(acc[13], x3.y, w);
        fma4(acc[14], x3.z, w); fma4(acc[15], x3.w, w);
    }
    #pragma unroll
    for (int v = 0; v < 16; v++)
        *(float4*)&ws[OFF_ARENA + kc * 147456 + (j * 64 + vg * 16 + v) * 768 + e4] = acc[v];
}

// reduce qk partials (12 kc) -> QK[p][b][d]. 144 blocks.
__global__ __launch_bounds__(256) void k_red_qk(float* ws) {
    int idx = blockIdx.x * 256 + threadIdx.x;
    int fidx = idx * 4;
    int p = fidx / 24576, rem = fidx % 24576;
    int b = rem / 768, d = rem % 768;
    int i = p / 2, c = p % 2, j = c + (c >= i ? 1 : 0);
    int i1 = (j == 0) ? 1 : 0;
    int iidx = (i == i1) ? 0 : 1;
    int vg = iidx * 32 + b;
    float4 a = make_float4(0.f, 0.f, 0.f, 0.f);
    #pragma unroll
    for (int kc = 0; kc < 12; kc++) {
        float4 pp = *(const float4*)&ws[OFF_ARENA + kc * 147456 + (j * 64 + vg) * 768 + d];
        a.x += pp.x; a.y += pp.y; a.z += pp.z; a.w += pp.w;
    }
    *(float4*)&ws[OFF_QK + fidx] = a;
}

// K4a: FUSED score + stats: one feats pass computes raw attention dots for both p's
// sharing key-modality (j,b) AND mu/lv/pkpre (+pqpre, KL). 384 blocks (j, b, kc 4).
__global__ __launch_bounds__(256) void k_score(const float* feats, float* ws) {
    int blk = blockIdx.x;
    int j = blk / 128, r = blk % 128, b = r / 4, kc = r % 4;
    int i1 = (j == 0) ? 1 : 0, i2 = (j == 2) ? 1 : 2;
    int pA = 2 * i1 + ((j < i1) ? j : j - 1);
    int pB = 2 * i2 + ((j < i2) ? j : j - 1);
    int wave = threadIdx.x >> 6, lane = threadIdx.x & 63;
    const float4* qa4 = (const float4*)(ws + OFF_QK + (pA * B + b) * D);
    const float4* qb4 = (const float4*)(ws + OFF_QK + (pB * B + b) * D);
    float4 qA0 = qa4[lane], qA1 = qa4[lane + 64], qA2 = qa4[lane + 128];
    float4 qB0 = qb4[lane], qB1 = qb4[lane + 64], qB2 = qb4[lane + 128];
    const float4* wmu4 = (const float4*)(ws + OFF_WMU + j * D);
    const float4* wlv4 = (const float4*)(ws + OFF_WLV + j * D);
    const float4* wk04 = (const float4*)(ws + OFF_WPK + pA * D);
    const float4* wk14 = (const float4*)(ws + OFF_WPK + pB * D);
    float4 U0 = wmu4[lane], U1 = wmu4[lane + 64], U2 = wmu4[lane + 128];
    float4 L0 = wlv4[lane], L1 = wlv4[lane + 64], L2 = wlv4[lane + 128];
    float4 K00 = wk04[lane], K01 = wk04[lane + 64], K02 = wk04[lane + 128];
    float4 K10 = wk14[lane], K11 = wk14[lane + 64], K12 = wk14[lane + 128];
    const float* fb = feats + ((j * B + b) * S) * D;
    float* scA = ws + OFF_ARENA + ((j * B + b) * 2) * S;
    float* scB = scA + S;
    float cmu = ws[OFF_CMU + j], clv = ws[OFF_CLV + j];
    float cpk0 = ws[OFF_CPK + pA], cpk1 = ws[OFF_CPK + pB];
    if (kc == 0 && wave == 0) {
        // pqpre for query-modality j at s=0 (row 0 is hot in L2 from the main loop below)
        const float4* wg4 = (const float4*)(ws + OFF_WPGQ + j * D);
        const float4* f0 = (const float4*)fb;
        float dd = dot4(f0[lane], wg4[lane]) + dot4(f0[lane + 64], wg4[lane + 64])
                 + dot4(f0[lane + 128], wg4[lane + 128]);
        dd = wave_reduce(dd);
        if (lane == 0) ws[OFF_PQPRE + j * B + b] = dd + ws[OFF_CPGQ + j];
    }
    int k0 = kc * 64 + wave * 16;
    float klsum = 0.f;
    for (int k = k0; k < k0 + 16; k += 2) {
        const float4* fA = (const float4*)(fb + k * D);
        const float4* fB = (const float4*)(fb + (k + 1) * D);
        float4 a0 = fA[lane], a1 = fA[lane + 64], a2 = fA[lane + 128];
        float4 b0 = fB[lane], b1 = fB[lane + 64], b2 = fB[lane + 128];
        float sa1 = dot4(a0, qA0) + dot4(a1, qA1) + dot4(a2, qA2);
        float sb1 = dot4(a0, qB0) + dot4(a1, qB1) + dot4(a2, qB2);
        float mu1 = dot4(a0, U0) + dot4(a1, U1) + dot4(a2, U2);
        float lv1 = dot4(a0, L0) + dot4(a1, L1) + dot4(a2, L2);
        float p01 = dot4(a0, K00) + dot4(a1, K01) + dot4(a2, K02);
        float p11 = dot4(a0, K10) + dot4(a1, K11) + dot4(a2, K12);
        float sa2 = dot4(b0, qA0) + dot4(b1, qA1) + dot4(b2, qA2);
        float sb2 = dot4(b0, qB0) + dot4(b1, qB1) + dot4(b2, qB2);
        float mu2 = dot4(b0, U0) + dot4(b1, U1) + dot4(b2, U2);
        float lv2 = dot4(b0, L0) + dot4(b1, L1) + dot4(b2, L2);
        float p02 = dot4(b0, K00) + dot4(b1, K01) + dot4(b2, K02);
        float p12 = dot4(b0, K10) + dot4(b1, K11) + dot4(b2, K12);
        sa1 = wave_reduce(sa1); sb1 = wave_reduce(sb1);
        mu1 = wave_reduce(mu1); lv1 = wave_reduce(lv1);
        p01 = wave_reduce(p01); p11 = wave_reduce(p11);
        sa2 = wave_reduce(sa2); sb2 = wave_reduce(sb2);
        mu2 = wave_reduce(mu2); lv2 = wave_reduce(lv2);
        p02 = wave_reduce(p02); p12 = wave_reduce(p12);
        if (lane == 0) {
            scA[k] = sa1; scB[k] = sb1; scA[k + 1] = sa2; scB[k + 1] = sb2;
            float m1 = mu1 + cmu, l1 = lv1 + clv;
            float m2 = mu2 + cmu, l2 = lv2 + clv;
            int row = (j * B + b) * S + k;
            ws[OFF_MU + row] = m1;      ws[OFF_MU + row + 1] = m2;
            ws[OFF_LV + row] = l1;      ws[OFF_LV + row + 1] = l2;
            ws[OFF_PKPRE + (pA * B + b) * S + k]     = p01 + cpk0;
            ws[OFF_PKPRE + (pA * B + b) * S + k + 1] = p02 + cpk0;
            ws[OFF_PKPRE + (pB * B + b) * S + k]     = p11 + cpk1;
            ws[OFF_PKPRE + (pB * B + b) * S + k + 1] = p12 + cpk1;
            // kl: reference adds kl_i twice (once per j!=i) → per-row weight is -(1+lv-mu^2-e^lv)
            klsum += 2.0f + l1 + l2 - m1 * m1 - m2 * m2 - __expf(l1) - __expf(l2);
        }
    }
    if (lane == 0) atomicAdd(ws + OFF_KL, -klsum);
}

// K4b: gates + softmax + weighted feats sum stripe. 288 blocks (j, b, dc 3).
__global__ __launch_bounds__(256) void k_wsum(const float* feats, const float* eps,
                                              const float* dyn, float* ws) {
    int blk = blockIdx.x;
    int j = blk / 96, r = blk % 96, b = r / 3, dc = r % 3;
    int i1 = (j == 0) ? 1 : 0, i2 = (j == 2) ? 1 : 2;
    int pA = 2 * i1 + ((j < i1) ? j : j - 1);
    int pB = 2 * i2 + ((j < i2) ? j : j - 1);
    __shared__ float sA[S], sB[S], redm[256];
    int t = threadIdx.x;
    float dynv = dyn[0];
    const float* rawA = ws + OFF_ARENA + ((j * B + b) * 2) * S;
    const float* rawB = rawA + S;
    {
        float muk = ws[OFF_MU + (i1 * B + b) * S + t];
        float lvk = ws[OFF_LV + (i1 * B + b) * S + t];
        float ek  = eps[(pA * B + b) * S + t];
        float g   = sigmoidf(muk + dynv * __expf(0.5f * lvk) * ek);
        float pk  = sigmoidf(ws[OFF_PKPRE + (pA * B + b) * S + t]) * g;
        float mu0 = ws[OFF_MU + (i1 * B + b) * S];
        float lv0 = ws[OFF_LV + (i1 * B + b) * S];
        float e0  = eps[(pA * B + b) * S];
        float g0  = sigmoidf(mu0 + dynv * __expf(0.5f * lv0) * e0);
        float pq  = sigmoidf(ws[OFF_PQPRE + i1 * B + b]) * g0;
        float qbk = ws[OFF_QBK + pA * B + b];
        sA[t] = (rawA[t] + qbk) * SCALE * pq * pk;
        muk = ws[OFF_MU + (i2 * B + b) * S + t];
        lvk = ws[OFF_LV + (i2 * B + b) * S + t];
        ek  = eps[(pB * B + b) * S + t];
        g   = sigmoidf(muk + dynv * __expf(0.5f * lvk) * ek);
        pk  = sigmoidf(ws[OFF_PKPRE + (pB * B + b) * S + t]) * g;
        mu0 = ws[OFF_MU + (i2 * B + b) * S];
        lv0 = ws[OFF_LV + (i2 * B + b) * S];
        e0  = eps[(pB * B + b) * S];
        g0  = sigmoidf(mu0 + dynv * __expf(0.5f * lv0) * e0);
        pq  = sigmoidf(ws[OFF_PQPRE + i2 * B + b]) * g0;
        qbk = ws[OFF_QBK + pB * B + b];
        sB[t] = (rawB[t] + qbk) * SCALE * pq * pk;
    }
    __syncthreads();
    redm[t] = sA[t]; __syncthreads();
    for (int st = 128; st > 0; st >>= 1) { if (t < st) redm[t] = fmaxf(redm[t], redm[t + st]); __syncthreads(); }
    float mxA = redm[0]; __syncthreads();
    float wA = __expf(sA[t] - mxA);
    redm[t] = wA; __syncthreads();
    for (int st = 128; st > 0; st >>= 1) { if (t < st) redm[t] += redm[t + st]; __syncthreads(); }
    float sumA = redm[0]; __syncthreads();
    sA[t] = wA / sumA;
    __syncthreads();
    redm[t] = sB[t]; __syncthreads();
    for (int st = 128; st > 0; st >>= 1) { if (t < st) redm[t] = fmaxf(redm[t], redm[t + st]); __syncthreads(); }
    float mxB = redm[0]; __syncthreads();
    float wB = __expf(sB[t] - mxB);
    redm[t] = wB; __syncthreads();
    for (int st = 128; st > 0; st >>= 1) { if (t < st) redm[t] += redm[t + st]; __syncthreads(); }
    float sumB = redm[0]; __syncthreads();
    sB[t] = wB / sumB;
    __syncthreads();
    int dim = dc * 256 + t;
    const float* fcol = feats + ((j * B + b) * S) * D + dim;
    float accA = 0.f, accB = 0.f;
    #pragma unroll 8
    for (int k = 0; k < S; k++) {
        float fv = fcol[k * D];
        accA += sA[k] * fv;
        accB += sB[k] * fv;
    }
    ws[OFF_FSUM + (pA * B + b) * D + dim] = accA;
    ws[OFF_FSUM + (pB * B + b) * D + dim] = accB;
}

// K5a: agg partials (2 Wv fused), 16 rows/block. 144 blocks (i 3, bg 2, kc 24 (32 k)).
__global__ __launch_bounds__(192) void k_agg(const float* Wv, float* ws) {
    int blk = blockIdx.x;
    int i = blk / 48, r = blk % 48, bg = r / 24, kc = r % 24;
    int kbase = kc * 32;
    int j0 = (i == 0) ? 1 : 0, j1 = (i == 2) ? 1 : 2;
    int p0 = 2 * i, p1 = 2 * i + 1;
    __shared__ __align__(16) float xs0[32][16], xs1[32][16];
    for (int idx = threadIdx.x; idx < 512; idx += 192) {
        int d = idx / 16, bb = idx % 16;
        xs0[d][bb] = ws[OFF_FSUM + (p0 * B + bg * 16 + bb) * D + kbase + d];
        xs1[d][bb] = ws[OFF_FSUM + (p1 * B + bg * 16 + bb) * D + kbase + d];
    }
    __syncthreads();
    int e4 = threadIdx.x * 4;
    const float* W0 = Wv + j0 * D * D + kbase * D + e4;
    const float* W1 = Wv + j1 * D * D + kbase * D + e4;
    float4 acc[16];
    #pragma unroll
    for (int bb = 0; bb < 16; bb++) acc[bb] = make_float4(0.f, 0.f, 0.f, 0.f);
    for (int k = 0; k < 32; k++) {
        float4 w0 = *(const float4*)(W0 + k * D);
        float4 w1 = *(const float4*)(W1 + k * D);
        float4 a0 = *(const float4*)&xs0[k][0];
        float4 a1 = *(const float4*)&xs0[k][4];
        float4 a2 = *(const float4*)&xs0[k][8];
        float4 a3 = *(const float4*)&xs0[k][12];
        float4 c0 = *(const float4*)&xs1[k][0];
        float4 c1 = *(const float4*)&xs1[k][4];
        float4 c2 = *(const float4*)&xs1[k][8];
        float4 c3 = *(const float4*)&xs1[k][12];
        fma4(acc[0], a0.x, w0);  fma4(acc[1], a0.y, w0);
        fma4(acc[2], a0.z, w0);  fma4(acc[3], a0.w, w0);
        fma4(acc[4], a1.x, w0);  fma4(acc[5], a1.y, w0);
        fma4(acc[6], a1.z, w0);  fma4(acc[7], a1.w, w0);
        fma4(acc[8], a2.x, w0);  fma4(acc[9], a2.y, w0);
        fma4(acc[10], a2.z, w0); fma4(acc[11], a2.w, w0);
        fma4(acc[12], a3.x, w0); fma4(acc[13], a3.y, w0);
        fma4(acc[14], a3.z, w0); fma4(acc[15], a3.w, w0);
        fma4(acc[0], c0.x, w1);  fma4(acc[1], c0.y, w1);
        fma4(acc[2], c0.z, w1);  fma4(acc[3], c0.w, w1);
        fma4(acc[4], c1.x, w1);  fma4(acc[5], c1.y, w1);
        fma4(acc[6], c1.z, w1);  fma4(acc[7], c1.w, w1);
        fma4(acc[8], c2.x, w1);  fma4(acc[9], c2.y, w1);
        fma4(acc[10], c2.z, w1); fma4(acc[11], c2.w, w1);
        fma4(acc[12], c3.x, w1); fma4(acc[13], c3.y, w1);
        fma4(acc[14], c3.z, w1); fma4(acc[15], c3.w, w1);
    }
    #pragma unroll
    for (int bb = 0; bb < 16; bb++)
        *(float4*)&ws[OFF_ARENA + kc * 73728 + (i * 32 + bg * 16 + bb) * 768 + e4] = acc[bb];
}

// reduce agg partials (24 kc) + bv biases. 72 blocks.
__global__ __launch_bounds__(256) void k_red_agg(const float* bv, float* ws) {
    int idx = blockIdx.x * 256 + threadIdx.x;
    int fidx = idx * 4;
    int i = fidx / 24576, e = fidx % 768;
    int j0 = (i == 0) ? 1 : 0, j1 = (i == 2) ? 1 : 2;
    float4 b0 = *(const float4*)&bv[j0 * 768 + e];
    float4 b1 = *(const float4*)&bv[j1 * 768 + e];
    float4 a = make_float4(b0.x + b1.x, b0.y + b1.y, b0.z + b1.z, b0.w + b1.w);
    const float* base = ws + OFF_ARENA;
    #pragma unroll
    for (int kc = 0; kc < 24; kc++) {
        float4 p = *(const float4*)&base[kc * 73728 + fidx];
        a.x += p.x; a.y += p.y; a.z += p.z; a.w += p.w;
    }
    *(float4*)&ws[OFF_AGG + fidx] = a;
}

// K5b: E/G partials, 16 rows/block. 144 blocks (kind 2, i 3, bg 2, kc 12 (64 k)).
__global__ __launch_bounds__(192) void k_eg(const float* WE_w, const float* Wh_w,
                                            const float* Wqc_w, float* ws) {
    int blk = blockIdx.x;
    int kind = blk / 72, r = blk % 72;
    int i = r / 24, r2 = r % 24, bg = r2 / 12, kc = r2 % 12;
    int kbase = kc * 64;
    __shared__ __align__(16) float xa[64][16], xq[64][16];
    for (int idx = threadIdx.x; idx < 1024; idx += 192) {
        int d = idx / 16, bb = idx % 16;
        xa[d][bb] = ws[OFF_AGG + (i * B + bg * 16 + bb) * D + kbase + d];
        if (kind) xq[d][bb] = ws[OFF_Q + (i * B + bg * 16 + bb) * D + kbase + d];
    }
    __syncthreads();
    int e4 = threadIdx.x * 4;
    float4 acc[16];
    #pragma unroll
    for (int bb = 0; bb < 16; bb++) acc[bb] = make_float4(0.f, 0.f, 0.f, 0.f);
    if (kind == 0) {
        const float* Wm = WE_w + i * D * D + kbase * D + e4;
        for (int k = 0; k < 64; k++) {
            float4 w = *(const float4*)(Wm + k * D);
            float4 a0 = *(const float4*)&xa[k][0];
            float4 a1 = *(const float4*)&xa[k][4];
            float4 a2 = *(const float4*)&xa[k][8];
            float4 a3 = *(const float4*)&xa[k][12];
            fma4(acc[0], a0.x, w);  fma4(acc[1], a0.y, w);
            fma4(acc[2], a0.z, w);  fma4(acc[3], a0.w, w);
            fma4(acc[4], a1.x, w);  fma4(acc[5], a1.y, w);
            fma4(acc[6], a1.z, w);  fma4(acc[7], a1.w, w);
            fma4(acc[8], a2.x, w);  fma4(acc[9], a2.y, w);
            fma4(acc[10], a2.z, w); fma4(acc[11], a2.w, w);
            fma4(acc[12], a3.x, w); fma4(acc[13], a3.y, w);
            fma4(acc[14], a3.z, w); fma4(acc[15], a3.w, w);
        }
    } else {
        const float* Wh = Wh_w + i * D * D + kbase * D + e4;
        const float* Wc = Wqc_w + i * D * D + kbase * D + e4;
        for (int k = 0; k < 64; k++) {
            float4 wh = *(const float4*)(Wh + k * D);
            float4 wc = *(const float4*)(Wc + k * D);
            float4 a0 = *(const float4*)&xa[k][0];
            float4 a1 = *(const float4*)&xa[k][4];
            float4 a2 = *(const float4*)&xa[k][8];
            float4 a3 = *(const float4*)&xa[k][12];
            float4 q0 = *(const float4*)&xq[k][0];
            float4 q1 = *(const float4*)&xq[k][4];
            float4 q2 = *(const float4*)&xq[k][8];
            float4 q3 = *(const float4*)&xq[k][12];
            fma4(acc[0], a0.x, wh);  fma4(acc[1], a0.y, wh);
            fma4(acc[2], a0.z, wh);  fma4(acc[3], a0.w, wh);
            fma4(acc[4], a1.x, wh);  fma4(acc[5], a1.y, wh);
            fma4(acc[6], a1.z, wh);  fma4(acc[7], a1.w, wh);
            fma4(acc[8], a2.x, wh);  fma4(acc[9], a2.y, wh);
            fma4(acc[10], a2.z, wh); fma4(acc[11], a2.w, wh);
            fma4(acc[12], a3.x, wh); fma4(acc[13], a3.y, wh);
            fma4(acc[14], a3.z, wh); fma4(acc[15], a3.w, wh);
            fma4(acc[0], q0.x, wc);  fma4(acc[1], q0.y, wc);
            fma4(acc[2], q0.z, wc);  fma4(acc[3], q0.w, wc);
            fma4(acc[4], q1.x, wc);  fma4(acc[5], q1.y, wc);
            fma4(acc[6], q1.z, wc);  fma4(acc[7], q1.w, wc);
            fma4(acc[8], q2.x, wc);  fma4(acc[9], q2.y, wc);
            fma4(acc[10], q2.z, wc); fma4(acc[11], q2.w, wc);
            fma4(acc[12], q3.x, wc); fma4(acc[13], q3.y, wc);
            fma4(acc[14], q3.z, wc); fma4(acc[15], q3.w, wc);
        }
    }
    int base = OFF_ARENA + (kind ? 884736 : 0) + kc * 73728;
    #pragma unroll
    for (int bb = 0; bb < 16; bb++)
        *(float4*)&ws[base + (i * 32 + bg * 16 + bb) * 768 + e4] = acc[bb];
}

// reduce E/G partials (12 kc) + bias + relu. 144 blocks (first 72: E, rest: G).
__global__ __launch_bounds__(256) void k_red_eg(const float* WE_b, const float* Wh_b,
                                                const float* Wqc_b, float* ws) {
    int blk = blockIdx.x;
    bool isG = blk >= 72;
    int idx = (isG ? blk - 72 : blk) * 256 + threadIdx.x;
    int fidx = idx * 4;
    int i = fidx / 24576, e = fidx % 768;
    float4 a;
    const float* base = ws + OFF_ARENA + (isG ? 884736 : 0);
    if (isG) {
        float4 b0 = *(const float4*)&Wh_b[i * 768 + e];
        float4 b1 = *(const float4*)&Wqc_b[i * 768 + e];
        a = make_float4(b0.x + b1.x, b0.y + b1.y, b0.z + b1.z, b0.w + b1.w);
    } else {
        a = *(const float4*)&WE_b[i * 768 + e];
    }
    #pragma unroll
    for (int kc = 0; kc < 12; kc++) {
        float4 p = *(const float4*)&base[kc * 73728 + fidx];
        a.x += p.x; a.y += p.y; a.z += p.z; a.w += p.w;
    }
    a.x = fmaxf(a.x, 0.f); a.y = fmaxf(a.y, 0.f); a.z = fmaxf(a.z, 0.f); a.w = fmaxf(a.w, 0.f);
    *(float4*)&ws[(isG ? OFF_G : OFF_E) + fidx] = a;
}

// K5c: LayerNorm(E)*LayerNorm(G) -> fused. 96 blocks (i,b).
__global__ __launch_bounds__(256) void k_ln(const float* lnE_g, const float* lnE_b,
        const float* lnG_g, const float* lnG_b, float* ws) {
    int blk = blockIdx.x;
    int i = blk / B, b = blk % B;
    const float* E = ws + OFF_E + (i * B + b) * D;
    const float* G = ws + OFF_G + (i * B + b) * D;
    int t = threadIdx.x;
    float e0 = E[t], e1 = E[t + 256], e2 = E[t + 512];
    float g0 = G[t], g1 = G[t + 256], g2 = G[t + 512];
    __shared__ float r1[256], r2[256], r3[256], r4[256];
    r1[t] = e0 + e1 + e2;
    r2[t] = e0 * e0 + e1 * e1 + e2 * e2;
    r3[t] = g0 + g1 + g2;
    r4[t] = g0 * g0 + g1 * g1 + g2 * g2;
    __syncthreads();
    for (int st = 128; st > 0; st >>= 1) {
        if (t < st) { r1[t] += r1[t + st]; r2[t] += r2[t + st]; r3[t] += r3[t + st]; r4[t] += r4[t + st]; }
        __syncthreads();
    }
    float mE = r1[0] * (1.0f / D), vE = r2[0] * (1.0f / D) - mE * mE;
    float mG = r3[0] * (1.0f / D), vG = r4[0] * (1.0f / D) - mG * mG;
    float sE = rsqrtf(vE + LN_EPS), sG = rsqrtf(vG + LN_EPS);
    float* o = ws + OFF_FUSED + b * MD + i * D;
    const float* eg = lnE_g + i * D; const float* ebv = lnE_b + i * D;
    const float* gg = lnG_g + i * D; const float* gbv = lnG_b + i * D;
    o[t]       = ((e0 - mE) * sE * eg[t]       + ebv[t])       * ((g0 - mG) * sG * gg[t]       + gbv[t]);
    o[t + 256] = ((e1 - mE) * sE * eg[t + 256] + ebv[t + 256]) * ((g1 - mG) * sG * gg[t + 256] + gbv[t + 256]);
    o[t + 512] = ((e2 - mE) * sE * eg[t + 512] + ebv[t + 512]) * ((g2 - mG) * sG * gg[t + 512] + gbv[t + 512]);
}

// K6: out partials, 16 rows/block. 72 blocks (bg 2 (16 b), kc 36 (64 f)). 256 threads.
__global__ __launch_bounds__(256) void k_out(const float* out_w, float* ws) {
    int blk = blockIdx.x;
    int bg = blk / 36, kc = blk % 36;
    int kbase = kc * 64;
    __shared__ __align__(16) float xs[64][16];
    for (int idx = threadIdx.x; idx < 1024; idx += 256) {
        int d = idx / 16, bb = idx % 16;
        xs[d][bb] = ws[OFF_FUSED + (bg * 16 + bb) * MD + kbase + d];
    }
    __syncthreads();
    int e4 = threadIdx.x * 4;
    const float* Wm = out_w + kbase * H + e4;
    float4 acc[16];
    #pragma unroll
    for (int bb = 0; bb < 16; bb++) acc[bb] = make_float4(0.f, 0.f, 0.f, 0.f);
    for (int k = 0; k < 64; k++) {
        float4 w = *(const float4*)(Wm + k * H);
        float4 x0 = *(const float4*)&xs[k][0];
        float4 x1 = *(const float4*)&xs[k][4];
        float4 x2 = *(const float4*)&xs[k][8];
        float4 x3 = *(const float4*)&xs[k][12];
        fma4(acc[0], x0.x, w);  fma4(acc[1], x0.y, w);
        fma4(acc[2], x0.z, w);  fma4(acc[3], x0.w, w);
        fma4(acc[4], x1.x, w);  fma4(acc[5], x1.y, w);
        fma4(acc[6], x1.z, w);  fma4(acc[7], x1.w, w);
        fma4(acc[8], x2.x, w);  fma4(acc[9], x2.y, w);
        fma4(acc[10], x2.z, w); fma4(acc[11], x2.w, w);
        fma4(acc[12], x3.x, w); fma4(acc[13], x3.y, w);
        fma4(acc[14], x3.z, w); fma4(acc[15], x3.w, w);
    }
    #pragma unroll
    for (int bb = 0; bb < 16; bb++)
        *(float4*)&ws[OFF_ARENA + kc * 32768 + (bg * 16 + bb) * 1024 + e4] = acc[bb];
}

// final: sum out partials (36 kc) + bias, write kl. 32 blocks (b).
__global__ __launch_bounds__(256) void k_fin(const float* out_b, float* ws, float* out) {
    int b = blockIdx.x;
    int h4 = threadIdx.x * 4;
    float4 a = *(const float4*)&out_b[h4];
    #pragma unroll
    for (int kc = 0; kc < 36; kc++) {
        float4 p = *(const float4*)&ws[OFF_ARENA + kc * 32768 + b * 1024 + h4];
        a.x += p.x; a.y += p.y; a.z += p.z; a.w += p.w;
    }
    *(float4*)&out[b * H + h4] = a;
    if (b == 0 && threadIdx.x == 0) out[B * H] = ws[OFF_KL];
}

extern "C" void kernel_launch(void* const* d_in, const int* in_sizes, int n_in,
                              void* d_out, int out_size, void* d_ws, size_t ws_size,
                              hipStream_t stream) {
    const float* feats = (const float*)d_in[0];
    const float* Wq    = (const float*)d_in[1];
    const float* bq    = (const float*)d_in[2];
    const float* Wk    = (const float*)d_in[3];
    const float* bk    = (const float*)d_in[4];
    const float* Wv    = (const float*)d_in[5];
    const float* bv    = (const float*)d_in[6];
    const float* pgq_w = (const float*)d_in[7];
    const float* pgq_b = (const float*)d_in[8];
    const float* pgk_w = (const float*)d_in[9];
    const float* pgk_b = (const float*)d_in[10];
    const float* mu_w  = (const float*)d_in[11];
    const float* mu_b  = (const float*)d_in[12];
    const float* lv_w  = (const float*)d_in[13];
    const float* lv_b  = (const float*)d_in[14];
    const float* dyn   = (const float*)d_in[15];
    const float* WE_w  = (const float*)d_in[16];
    const float* WE_b  = (const float*)d_in[17];
    const float* Wh_w  = (const float*)d_in[18];
    const float* Wh_b  = (const float*)d_in[19];
    const float* Wqc_w = (const float*)d_in[20];
    const float* Wqc_b = (const float*)d_in[21];
    const float* lnE_g = (const float*)d_in[22];
    const float* lnE_b = (const float*)d_in[23];
    const float* lnG_g = (const float*)d_in[24];
    const float* lnG_b = (const float*)d_in[25];
    const float* out_w = (const float*)d_in[26];
    const float* out_b = (const float*)d_in[27];
    const float* eps   = (const float*)d_in[28];
    float* ws  = (float*)d_ws;
    float* out = (float*)d_out;

    k_prep<<<519, 256, 0, stream>>>(Wq, Wk, bq, bk, mu_w, mu_b, lv_w, lv_b,
                                    pgq_w, pgq_b, pgk_w, pgk_b, ws);
    k_qrow<<<144, 192, 0, stream>>>(feats, Wq, ws);
    k_red_q<<<96, 256, 0, stream>>>(bq, bk, ws);
    k_qk<<<144, 192, 0, stream>>>(ws);
    k_red_qk<<<144, 256, 0, stream>>>(ws);
    k_score<<<384, 256, 0, stream>>>(feats, ws);
    k_wsum<<<288, 256, 0, stream>>>(feats, eps, dyn, ws);
    k_agg<<<144, 192, 0, stream>>>(Wv, ws);
    k_red_agg<<<72, 256, 0, stream>>>(bv, ws);
    k_eg<<<144, 192, 0, stream>>>(WE_w, Wh_w, Wqc_w, ws);
    k_red_eg<<<144, 256, 0, stream>>>(WE_b, Wh_b, Wqc_b, ws);
    k_ln<<<M * B, 256, 0, stream>>>(lnE_g, lnE_b, lnG_g, lnG_b, ws);
    k_out<<<72, 256, 0, stream>>>(out_w, ws);
    k_fin<<<32, 256, 0, stream>>>(out_b, ws, out);
}